// Round 4
// baseline (693.197 us; speedup 1.0000x reference)
//
#include <hip/hip_runtime.h>
#include <math.h>

#define HW 65536
#define WID 256
#define HEI 256
#define NB 2
#define NFG 20
#define NMAP 40
#define CH 256
#define CSEG 21
#define TK 100

__device__ __constant__ float c_GX[25] = {
  2.f,1.f,1e-6f,-1.f,-2.f,
  3.f,2.f,1e-6f,-2.f,-3.f,
  4.f,3.f,0.f,-3.f,-4.f,
  3.f,2.f,1e-6f,-2.f,-3.f,
  2.f,1.f,1e-6f,-1.f,-2.f};
__device__ __constant__ float c_GY[25] = {
  2.f,3.f,4.f,3.f,2.f,
  1.f,2.f,3.f,2.f,1.f,
  1e-6f,1e-6f,1e-6f,1e-6f,1e-6f,
  -1.f,-2.f,-3.f,-2.f,-1.f,
  -2.f,-3.f,-4.f,-3.f,-2.f};

// ---------------- K1: softmax(seg_map * 1000, axis=ch)[:,1:] in f64 ------------
__global__ void k_seg(const float* __restrict__ seg_map, double* __restrict__ seg) {
  int idx = blockIdx.x * blockDim.x + threadIdx.x;
  if (idx >= NB * HW) return;
  int b = idx / HW, p = idx % HW;
  double x[CSEG];
  double m = -INFINITY;
  #pragma unroll
  for (int c = 0; c < CSEG; ++c) {
    double v = (double)seg_map[(size_t)(b * CSEG + c) * HW + p] * 1000.0;
    x[c] = v;
    m = fmax(m, v);
  }
  double s = 0.0;
  #pragma unroll
  for (int c = 0; c < CSEG; ++c) { double e = exp(x[c] - m); x[c] = e; s += e; }
  #pragma unroll
  for (int c = 1; c < CSEG; ++c)
    seg[(size_t)(b * NFG + (c - 1)) * HW + p] = x[c] / s;
}

// ---------------- K2: Sobel (cross-correlation, SAME zero-pad) + mag + quantize, f64
__global__ void k_sobel(const double* __restrict__ seg, const float* __restrict__ label,
                        double* __restrict__ mag, unsigned char* __restrict__ qb) {
  int idx = blockIdx.x * blockDim.x + threadIdx.x;
  if (idx >= NMAP * HW) return;
  int mapi = idx / HW, p = idx % HW;
  int y = p / WID, x = p % WID;
  const double* im = seg + (size_t)mapi * HW;
  double gx = 0.0, gy = 0.0;
  #pragma unroll
  for (int dy = 0; dy < 5; ++dy) {
    int yy = y + dy - 2;
    if (yy < 0 || yy >= HEI) continue;
    #pragma unroll
    for (int dx = 0; dx < 5; ++dx) {
      int xx = x + dx - 2;
      if (xx < 0 || xx >= WID) continue;
      double v = im[yy * WID + xx];
      gx += v * (double)c_GX[dy * 5 + dx];
      gy += v * (double)c_GY[dy * 5 + dx];
    }
  }
  int b = mapi / NFG, c = mapi % NFG;
  double lab = (double)label[b * CSEG + c + 1];
  gx *= lab;
  gy *= lab;
  double mg = sqrt(gx * gx + gy * gy + 1e-8);
  double o = atan2(gy, gx);
  const double DIVQ = 3.1416 / 8.0;
  const double T1 = DIVQ;
  const double T3 = 3.0 * DIVQ;
  const double T5 = 5.0 * DIVQ;
  const double T7 = 7.0 * DIVQ;
  const double T8 = 8.0 * DIVQ;
  int qv;
  if (o >= T1 && o < T3) qv = 0;
  else if (o >= T3 && o < T5) qv = 1;
  else if (o >= T5 && o < T7) qv = 2;
  else if ((o >= T7 && o < T8) || (o >= -T8 && o < -T7)) qv = 3;
  else if (o >= -T7 && o < -T5) qv = 4;
  else if (o >= -T5 && o < -T3) qv = 5;
  else if (o >= -T3 && o < -T1) qv = 6;
  else if (o >= -T1 && o < T1) qv = 7;
  else qv = 3;
  mag[idx] = mg;
  qb[idx] = (unsigned char)qv;
}

// ---------------- K3: exact top-100 per map, f64 keys --------------------------
// Radix-select the 100th-largest VALUE; take all strictly-greater, then the
// need_eq LARGEST-index equal elements (numpy argsort[::-1] tie semantics:
// ascending stable sort reversed puts larger indices first among ties).
__global__ void k_topk(const double* __restrict__ mag, int* __restrict__ pos) {
  int mapi = blockIdx.x;
  const double* m = mag + (size_t)mapi * HW;
  __shared__ unsigned int hist[256];
  __shared__ unsigned long long s_pfx, s_msk;
  __shared__ int s_r, s_cnt, s_eqtot;
  __shared__ int cnts[256];
  int tid = threadIdx.x;
  if (tid == 0) { s_pfx = 0ull; s_msk = 0ull; s_r = TK; }
  __syncthreads();
  for (int round = 0; round < 8; ++round) {
    int shift = 56 - 8 * round;
    hist[tid] = 0;
    __syncthreads();
    unsigned long long pfx = s_pfx, msk = s_msk;
    for (int i = tid; i < HW; i += 256) {
      unsigned long long key = (unsigned long long)__double_as_longlong(m[i]);
      if ((key & msk) == pfx)
        atomicAdd(&hist[(unsigned int)(key >> shift) & 0xFFu], 1u);
    }
    __syncthreads();
    if (tid == 0) {
      int r = s_r, cum = 0, bsel = 0;
      for (int b2 = 255; b2 >= 0; --b2) {
        int nc = cum + (int)hist[b2];
        if (nc >= r) { bsel = b2; s_r = r - cum; break; }
        cum = nc;
      }
      s_pfx = pfx | ((unsigned long long)bsel << shift);
      s_msk = msk | (0xFFull << shift);
    }
    __syncthreads();
  }
  unsigned long long kv = s_pfx;   // bit pattern of the 100th-largest value
  int need_eq = s_r;               // how many ==kv elements belong in the top-K (>=1)
  if (tid == 0) s_cnt = 0;
  __syncthreads();
  // contiguous chunk per thread -> ascending global index order within/across threads
  const int CHUNK = HW / 256;
  int base_i = tid * CHUNK;
  int myeq = 0;
  for (int k = 0; k < CHUNK; ++k) {
    int i = base_i + k;
    unsigned long long key = (unsigned long long)__double_as_longlong(m[i]);
    if (key > kv) {
      int slot = atomicAdd(&s_cnt, 1);
      pos[mapi * TK + slot] = i;        // set semantics; order irrelevant
    } else if (key == kv) {
      ++myeq;
    }
  }
  cnts[tid] = myeq;
  __syncthreads();
  if (tid == 0) {                        // exclusive prefix sum + total
    int run = 0;
    for (int t2 = 0; t2 < 256; ++t2) { int c2 = cnts[t2]; cnts[t2] = run; run += c2; }
    s_eqtot = run;
  }
  __syncthreads();
  int rank = cnts[tid];                  // ascending-index rank of my first equal
  int lo = s_eqtot - need_eq;            // keep equals with rank >= lo (largest indices)
  int wbase = TK - need_eq;              // == number of strictly-greater elements
  for (int k = 0; k < CHUNK; ++k) {
    int i = base_i + k;
    unsigned long long key = (unsigned long long)__double_as_longlong(m[i]);
    if (key == kv) {
      if (rank >= lo) pos[mapi * TK + wbase + (rank - lo)] = i;
      ++rank;
    }
  }
}

// ---------------- K4: indices, validity, gather + per-column f64 softmax ---------
__global__ void k_gather(const float* __restrict__ dense_ft, const float* __restrict__ maskp,
                         const unsigned char* __restrict__ qb, const int* __restrict__ pos,
                         double* __restrict__ outs, double* __restrict__ ins,
                         double* __restrict__ outs_m, double* __restrict__ ins_m,
                         int* __restrict__ voutArr, int* __restrict__ vinArr) {
  int blk = blockIdx.x;
  int mapi = blk / TK, j = blk % TK;
  int b = mapi / NFG;
  int tid = threadIdx.x;
  int p = pos[mapi * TK + j];
  int o = (int)qb[(size_t)mapi * HW + p] + 1;
  int mod4 = ((o & 3) == 0) ? 1 : 0;
  int horiz = (o == 2 || o == 6) ? 1 : 0;
  int po = (o < 4) ? 25 : -5;   // STEP*STEP : -STEP
  int pi = (o < 4) ? -5 : 1;
  int so = ((o & 1) == 0) ? -1 : 1;
  int si = -so;
  int out_idx = p + po * mod4 * WID + so * horiz;
  int in_idx  = p + pi * mod4 * WID + si * horiz;
  int ro = out_idx % 255; if (ro < 0) ro += 255;   // python floored mod
  int ri = in_idx  % 255; if (ri < 0) ri += 255;
  int vo = (ro != 0 && ro != 1 && out_idx > 0 && out_idx < HW - 1) ? 1 : 0;
  int vi = (ri != 0 && ri != 1 && in_idx  > 0 && in_idx  < HW - 1) ? 1 : 0;
  int oi = out_idx < 0 ? 0 : (out_idx > HW - 1 ? HW - 1 : out_idx);
  int ii = in_idx  < 0 ? 0 : (in_idx  > HW - 1 ? HW - 1 : in_idx);
  if (tid == 0) { voutArr[mapi * TK + j] = vo; vinArr[mapi * TK + j] = vi; }

  __shared__ double red[256];
  // dense @ oi -> outs
  {
    double x = (double)dense_ft[(size_t)(b * CH + tid) * HW + oi];
    red[tid] = x; __syncthreads();
    for (int s = 128; s > 0; s >>= 1) { if (tid < s) red[tid] = fmax(red[tid], red[tid + s]); __syncthreads(); }
    double mx = red[0]; __syncthreads();
    double e = exp(x - mx);
    red[tid] = e; __syncthreads();
    for (int s = 128; s > 0; s >>= 1) { if (tid < s) red[tid] += red[tid + s]; __syncthreads(); }
    double sm = red[0]; __syncthreads();
    outs[((size_t)mapi * TK + j) * CH + tid] = e / sm;
  }
  // dense @ ii -> ins
  {
    double x = (double)dense_ft[(size_t)(b * CH + tid) * HW + ii];
    red[tid] = x; __syncthreads();
    for (int s = 128; s > 0; s >>= 1) { if (tid < s) red[tid] = fmax(red[tid], red[tid + s]); __syncthreads(); }
    double mx = red[0]; __syncthreads();
    double e = exp(x - mx);
    red[tid] = e; __syncthreads();
    for (int s = 128; s > 0; s >>= 1) { if (tid < s) red[tid] += red[tid + s]; __syncthreads(); }
    double sm = red[0]; __syncthreads();
    ins[((size_t)mapi * TK + j) * CH + tid] = e / sm;
  }
  // mask @ oi -> outs_m
  {
    double y = (tid < CSEG) ? (double)maskp[(size_t)(b * CSEG + tid) * HW + oi] : -INFINITY;
    red[tid] = y; __syncthreads();
    for (int s = 128; s > 0; s >>= 1) { if (tid < s) red[tid] = fmax(red[tid], red[tid + s]); __syncthreads(); }
    double mx = red[0]; __syncthreads();
    double e = (tid < CSEG) ? exp(y - mx) : 0.0;
    red[tid] = e; __syncthreads();
    for (int s = 128; s > 0; s >>= 1) { if (tid < s) red[tid] += red[tid + s]; __syncthreads(); }
    double sm = red[0]; __syncthreads();
    if (tid < CSEG) outs_m[((size_t)mapi * TK + j) * CSEG + tid] = e / sm;
    __syncthreads();
  }
  // mask @ ii -> ins_m
  {
    double y = (tid < CSEG) ? (double)maskp[(size_t)(b * CSEG + tid) * HW + ii] : -INFINITY;
    red[tid] = y; __syncthreads();
    for (int s = 128; s > 0; s >>= 1) { if (tid < s) red[tid] = fmax(red[tid], red[tid + s]); __syncthreads(); }
    double mx = red[0]; __syncthreads();
    double e = (tid < CSEG) ? exp(y - mx) : 0.0;
    red[tid] = e; __syncthreads();
    for (int s = 128; s > 0; s >>= 1) { if (tid < s) red[tid] += red[tid + s]; __syncthreads(); }
    double sm = red[0]; __syncthreads();
    if (tid < CSEG) ins_m[((size_t)mapi * TK + j) * CSEG + tid] = e / sm;
  }
}

// ---------------- K5: per-map statistics + beacon in f64 (sim never materialized)
__global__ void k_stats(const double* __restrict__ outs, const double* __restrict__ ins,
                        const double* __restrict__ outs_m, const double* __restrict__ ins_m,
                        const int* __restrict__ voutArr, const int* __restrict__ vinArr,
                        const float* __restrict__ label, double* __restrict__ lossmap) {
  int mapi = blockIdx.x, tid = threadIdx.x;
  int b = mapi / NFG, c = mapi % NFG;
  __shared__ double fvo[TK], fvi[TK];
  __shared__ double avi[CH], avo[CH], avim[CSEG], avom[CSEG];
  __shared__ double rm[TK], cm[TK], rmm[TK], cmm[TK];
  __shared__ double s_sfvo, s_sfvi;
  if (tid < TK) {
    fvo[tid] = (double)voutArr[mapi * TK + tid];
    fvi[tid] = (double)vinArr[mapi * TK + tid];
  }
  __syncthreads();
  if (tid == 0) {
    double a = 0.0, d = 0.0;
    for (int j2 = 0; j2 < TK; ++j2) { a += fvo[j2]; d += fvi[j2]; }
    s_sfvo = a; s_sfvi = d;
  }
  const double* OUT  = outs   + (size_t)mapi * TK * CH;
  const double* IN   = ins    + (size_t)mapi * TK * CH;
  const double* OUTm = outs_m + (size_t)mapi * TK * CSEG;
  const double* INm  = ins_m  + (size_t)mapi * TK * CSEG;
  {
    double a = 0.0, d = 0.0;
    for (int j2 = 0; j2 < TK; ++j2) {
      a += IN[j2 * CH + tid] * fvi[j2];
      d += OUT[j2 * CH + tid] * fvo[j2];
    }
    avi[tid] = a; avo[tid] = d;
  }
  if (tid < CSEG) {
    double a = 0.0, d = 0.0;
    for (int j2 = 0; j2 < TK; ++j2) {
      a += INm[j2 * CSEG + tid] * fvi[j2];
      d += OUTm[j2 * CSEG + tid] * fvo[j2];
    }
    avim[tid] = a; avom[tid] = d;
  }
  __syncthreads();
  double ci = fmax(s_sfvi, 1.0), co = fmax(s_sfvo, 1.0);
  if (tid < TK) {
    double d1 = 0.0, d2 = 0.0, d3 = 0.0, d4 = 0.0;
    for (int e = 0; e < CH; ++e) { d1 += OUT[tid * CH + e] * avi[e]; d2 += IN[tid * CH + e] * avo[e]; }
    for (int e = 0; e < CSEG; ++e) { d3 += OUTm[tid * CSEG + e] * avim[e]; d4 += INm[tid * CSEG + e] * avom[e]; }
    rm[tid] = d1 / ci; cm[tid] = d2 / co; rmm[tid] = d3 / ci; cmm[tid] = d4 / co;
  }
  __syncthreads();
  if (tid == 0) {
    double g = 0.0, gm = 0.0;
    for (int e = 0; e < CH; ++e) g += avo[e] * avi[e];
    for (int e = 0; e < CSEG; ++e) gm += avom[e] * avim[e];
    double den = fmax(s_sfvo * s_sfvi, 1.0);
    g /= den; gm /= den;
    double loss = 0.0;
    { // row beacon: sgn_mask = rmm>gm, sgn_dense = rm>g, vals = rm, v = fvo
      double s[4] = {0, 0, 0, 0}, cn[4] = {0, 0, 0, 0};
      for (int j2 = 0; j2 < TK; ++j2) {
        int smv = rmm[j2] > gm;
        int dmv = rm[j2] > g;
        int cat = smv ? (dmv ? 3 : 0) : (dmv ? 1 : 2);  // FP,FN,TP,TN = 0,1,2,3
        s[cat] += rm[j2] * fvo[j2];
        cn[cat] += fvo[j2];
      }
      const double sg[4] = {-1.0, 1.0, 1.0, -1.0};
      for (int t = 0; t < 4; ++t)
        if (cn[t] > 0.0) loss += sg[t] * (s[t] / fmax(cn[t], 1.0));
    }
    { // col beacon: sgn_mask = cmm>gm, sgn_dense = cm>g, vals = cm, v = fvi
      double s[4] = {0, 0, 0, 0}, cn[4] = {0, 0, 0, 0};
      for (int j2 = 0; j2 < TK; ++j2) {
        int smv = cmm[j2] > gm;
        int dmv = cm[j2] > g;
        int cat = smv ? (dmv ? 3 : 0) : (dmv ? 1 : 2);
        s[cat] += cm[j2] * fvi[j2];
        cn[cat] += fvi[j2];
      }
      const double sg[4] = {-1.0, 1.0, 1.0, -1.0};
      for (int t = 0; t < 4; ++t)
        if (cn[t] > 0.0) loss += sg[t] * (s[t] / fmax(cn[t], 1.0));
    }
    float lab = label[b * CSEG + c + 1];
    double gate = (s_sfvi >= 10.0 && s_sfvo >= 10.0 && lab > 0.f) ? 1.0 : 0.0;
    lossmap[mapi] = loss * gate;
  }
}

// ---------------- K6: deterministic ordered final sum --------------------------
__global__ void k_final(const double* __restrict__ lossmap, float* __restrict__ out) {
  if (threadIdx.x == 0 && blockIdx.x == 0) {
    double s = 0.0;
    for (int i = 0; i < NMAP; ++i) s += lossmap[i];
    out[0] = (float)s;
  }
}

extern "C" void kernel_launch(void* const* d_in, const int* in_sizes, int n_in,
                              void* d_out, int out_size, void* d_ws, size_t ws_size,
                              hipStream_t stream) {
  const float* seg_map  = (const float*)d_in[0];
  const float* dense_ft = (const float*)d_in[1];
  const float* maskp    = (const float*)d_in[2];
  const float* label    = (const float*)d_in[3];
  float* outp = (float*)d_out;

  char* w = (char*)d_ws;
  double* seg = (double*)w;               w += (size_t)NB * NFG * HW * 8;
  double* mag = (double*)w;               w += (size_t)NMAP * HW * 8;
  double* outs   = (double*)w;            w += (size_t)NMAP * TK * CH * 8;
  double* ins    = (double*)w;            w += (size_t)NMAP * TK * CH * 8;
  double* outs_m = (double*)w;            w += (size_t)NMAP * TK * CSEG * 8;
  double* ins_m  = (double*)w;            w += (size_t)NMAP * TK * CSEG * 8;
  double* lossmap = (double*)w;           w += (size_t)NMAP * 8;
  int* pos  = (int*)w;                    w += (size_t)NMAP * TK * 4;
  int* vout = (int*)w;                    w += (size_t)NMAP * TK * 4;
  int* vin  = (int*)w;                    w += (size_t)NMAP * TK * 4;
  unsigned char* qb = (unsigned char*)w;  w += (size_t)NMAP * HW;

  k_seg<<<(NB * HW + 255) / 256, 256, 0, stream>>>(seg_map, seg);
  k_sobel<<<(NMAP * HW + 255) / 256, 256, 0, stream>>>(seg, label, mag, qb);
  k_topk<<<NMAP, 256, 0, stream>>>(mag, pos);
  k_gather<<<NMAP * TK, 256, 0, stream>>>(dense_ft, maskp, qb, pos, outs, ins,
                                          outs_m, ins_m, vout, vin);
  k_stats<<<NMAP, 256, 0, stream>>>(outs, ins, outs_m, ins_m, vout, vin, label, lossmap);
  k_final<<<1, 64, 0, stream>>>(lossmap, outp);
}

// Round 5
// 499.218 us; speedup vs baseline: 1.3886x; 1.3886x over previous
//
#include <hip/hip_runtime.h>
#include <math.h>

#define HW 65536
#define WID 256
#define HEI 256
#define NB 2
#define NFG 20
#define NMAP 40
#define CH 256
#define CSEG 21
#define TK 100
#define PARTS 16
#define PARTN (HW / PARTS)    // 4096
#define CAND (PARTS * TK)     // 1600

__device__ __constant__ float c_GX[25] = {
  2.f,1.f,1e-6f,-1.f,-2.f,
  3.f,2.f,1e-6f,-2.f,-3.f,
  4.f,3.f,0.f,-3.f,-4.f,
  3.f,2.f,1e-6f,-2.f,-3.f,
  2.f,1.f,1e-6f,-1.f,-2.f};
__device__ __constant__ float c_GY[25] = {
  2.f,3.f,4.f,3.f,2.f,
  1.f,2.f,3.f,2.f,1.f,
  1e-6f,1e-6f,1e-6f,1e-6f,1e-6f,
  -1.f,-2.f,-3.f,-2.f,-1.f,
  -2.f,-3.f,-4.f,-3.f,-2.f};

// ---------------- K1: softmax(seg_map * 1000, axis=ch)[:,1:] in f64 ------------
__global__ void k_seg(const float* __restrict__ seg_map, double* __restrict__ seg) {
  int idx = blockIdx.x * blockDim.x + threadIdx.x;
  if (idx >= NB * HW) return;
  int b = idx / HW, p = idx % HW;
  double x[CSEG];
  double m = -INFINITY;
  #pragma unroll
  for (int c = 0; c < CSEG; ++c) {
    double v = (double)seg_map[(size_t)(b * CSEG + c) * HW + p] * 1000.0;
    x[c] = v;
    m = fmax(m, v);
  }
  double s = 0.0;
  #pragma unroll
  for (int c = 0; c < CSEG; ++c) { double e = exp(x[c] - m); x[c] = e; s += e; }
  #pragma unroll
  for (int c = 1; c < CSEG; ++c)
    seg[(size_t)(b * NFG + (c - 1)) * HW + p] = x[c] / s;
}

// ---------------- K2: Sobel (cross-correlation, SAME zero-pad) + mag + quantize, f64
__global__ void k_sobel(const double* __restrict__ seg, const float* __restrict__ label,
                        double* __restrict__ mag, unsigned char* __restrict__ qb) {
  int idx = blockIdx.x * blockDim.x + threadIdx.x;
  if (idx >= NMAP * HW) return;
  int mapi = idx / HW, p = idx % HW;
  int y = p / WID, x = p % WID;
  const double* im = seg + (size_t)mapi * HW;
  double gx = 0.0, gy = 0.0;
  #pragma unroll
  for (int dy = 0; dy < 5; ++dy) {
    int yy = y + dy - 2;
    if (yy < 0 || yy >= HEI) continue;
    #pragma unroll
    for (int dx = 0; dx < 5; ++dx) {
      int xx = x + dx - 2;
      if (xx < 0 || xx >= WID) continue;
      double v = im[yy * WID + xx];
      gx += v * (double)c_GX[dy * 5 + dx];
      gy += v * (double)c_GY[dy * 5 + dx];
    }
  }
  int b = mapi / NFG, c = mapi % NFG;
  double lab = (double)label[b * CSEG + c + 1];
  gx *= lab;
  gy *= lab;
  double mg = sqrt(gx * gx + gy * gy + 1e-8);
  double o = atan2(gy, gx);
  const double DIVQ = 3.1416 / 8.0;
  const double T1 = DIVQ;
  const double T3 = 3.0 * DIVQ;
  const double T5 = 5.0 * DIVQ;
  const double T7 = 7.0 * DIVQ;
  const double T8 = 8.0 * DIVQ;
  int qv;
  if (o >= T1 && o < T3) qv = 0;
  else if (o >= T3 && o < T5) qv = 1;
  else if (o >= T5 && o < T7) qv = 2;
  else if ((o >= T7 && o < T8) || (o >= -T8 && o < -T7)) qv = 3;
  else if (o >= -T7 && o < -T5) qv = 4;
  else if (o >= -T5 && o < -T3) qv = 5;
  else if (o >= -T3 && o < -T1) qv = 6;
  else if (o >= -T1 && o < T1) qv = 7;
  else qv = 3;
  mag[idx] = mg;
  qb[idx] = (unsigned char)qv;
}

// ---------------- K3a: per-part exact top-100 (LDS-resident radix select) -------
// Each block: 4096-element slice -> LDS once -> 8-round radix select of the
// 100th-largest value -> emit 100 candidates under (value desc, index desc)
// total order (numpy argsort[::-1] tie semantics: largest index first).
// Every global-top-100 element is in its part's local top-100.
__global__ void k_topk_part(const double* __restrict__ mag,
                            unsigned long long* __restrict__ ckey,
                            int* __restrict__ cidx) {
  int mapi = blockIdx.x / PARTS, part = blockIdx.x % PARTS;
  const double* m = mag + (size_t)mapi * HW + (size_t)part * PARTN;
  __shared__ unsigned long long sk[PARTN];      // 32 KiB
  __shared__ unsigned int hist[256];
  __shared__ unsigned long long s_pfx, s_msk;
  __shared__ int s_r, s_cnt, s_eqtot;
  __shared__ int cnts[256];
  int tid = threadIdx.x;
  for (int i = tid; i < PARTN; i += 256)
    sk[i] = (unsigned long long)__double_as_longlong(m[i]);
  if (tid == 0) { s_pfx = 0ull; s_msk = 0ull; s_r = TK; s_cnt = 0; }
  __syncthreads();
  for (int round = 0; round < 8; ++round) {
    int shift = 56 - 8 * round;
    hist[tid] = 0;
    __syncthreads();
    unsigned long long pfx = s_pfx, msk = s_msk;
    for (int i = tid; i < PARTN; i += 256) {
      unsigned long long key = sk[i];
      if ((key & msk) == pfx)
        atomicAdd(&hist[(unsigned int)(key >> shift) & 0xFFu], 1u);
    }
    __syncthreads();
    if (tid == 0) {
      int r = s_r, cum = 0, bsel = 0;
      for (int b2 = 255; b2 >= 0; --b2) {
        int nc = cum + (int)hist[b2];
        if (nc >= r) { bsel = b2; s_r = r - cum; break; }
        cum = nc;
      }
      s_pfx = pfx | ((unsigned long long)bsel << shift);
      s_msk = msk | (0xFFull << shift);
    }
    __syncthreads();
  }
  unsigned long long kv = s_pfx;   // block-local 100th-largest value (bit pattern)
  int need_eq = s_r;               // equals needed (>=1); greater_cnt = TK - need_eq
  unsigned long long* outk = ckey + (size_t)mapi * CAND + (size_t)part * TK;
  int* outi = cidx + (size_t)mapi * CAND + (size_t)part * TK;
  int gbase = part * PARTN;        // map-local index base of this slice
  const int CH2 = PARTN / 256;     // 16, contiguous chunk per thread (index order)
  int base = tid * CH2;
  int myeq = 0;
  for (int k = 0; k < CH2; ++k) {
    unsigned long long key = sk[base + k];
    if (key > kv) {
      int slot = atomicAdd(&s_cnt, 1);         // set semantics; order irrelevant
      outk[slot] = key; outi[slot] = gbase + base + k;
    } else if (key == kv) ++myeq;
  }
  cnts[tid] = myeq;
  __syncthreads();
  if (tid == 0) {
    int run = 0;
    for (int t2 = 0; t2 < 256; ++t2) { int c2 = cnts[t2]; cnts[t2] = run; run += c2; }
    s_eqtot = run;
  }
  __syncthreads();
  int rank = cnts[tid];
  int lo = s_eqtot - need_eq;      // keep equals with rank >= lo (largest indices)
  int wb = TK - need_eq;
  for (int k = 0; k < CH2; ++k) {
    unsigned long long key = sk[base + k];
    if (key == kv) {
      if (rank >= lo) { outk[wb + rank - lo] = key; outi[wb + rank - lo] = gbase + base + k; }
      ++rank;
    }
  }
}

// ---------------- K3b: merge 1600 candidates -> exact global top-100 ------------
// Candidates provably contain all strictly-greater elements AND all boundary
// equals of the global cutoff, so radix-select over candidates = global select.
__global__ void k_topk_merge(const unsigned long long* __restrict__ ckey,
                             const int* __restrict__ cidx, int* __restrict__ pos) {
  int mapi = blockIdx.x, tid = threadIdx.x;
  __shared__ unsigned long long k_[CAND];       // 12.8 KiB
  __shared__ int i_[CAND];                      // 6.4 KiB
  __shared__ int eqi[CAND];                     // 6.4 KiB
  __shared__ unsigned int hist[256];
  __shared__ unsigned long long s_pfx, s_msk;
  __shared__ int s_r, s_cnt, s_eqn;
  for (int c = tid; c < CAND; c += 256) {
    k_[c] = ckey[(size_t)mapi * CAND + c];
    i_[c] = cidx[(size_t)mapi * CAND + c];
  }
  if (tid == 0) { s_pfx = 0ull; s_msk = 0ull; s_r = TK; s_cnt = 0; s_eqn = 0; }
  __syncthreads();
  for (int round = 0; round < 8; ++round) {
    int shift = 56 - 8 * round;
    hist[tid] = 0;
    __syncthreads();
    unsigned long long pfx = s_pfx, msk = s_msk;
    for (int c = tid; c < CAND; c += 256) {
      unsigned long long key = k_[c];
      if ((key & msk) == pfx)
        atomicAdd(&hist[(unsigned int)(key >> shift) & 0xFFu], 1u);
    }
    __syncthreads();
    if (tid == 0) {
      int r = s_r, cum = 0, bsel = 0;
      for (int b2 = 255; b2 >= 0; --b2) {
        int nc = cum + (int)hist[b2];
        if (nc >= r) { bsel = b2; s_r = r - cum; break; }
        cum = nc;
      }
      s_pfx = pfx | ((unsigned long long)bsel << shift);
      s_msk = msk | (0xFFull << shift);
    }
    __syncthreads();
  }
  unsigned long long kv = s_pfx;   // global 100th-largest value
  int need_eq = s_r;
  __syncthreads();
  for (int c = tid; c < CAND; c += 256) {
    unsigned long long key = k_[c];
    if (key > kv) {
      int slot = atomicAdd(&s_cnt, 1);
      pos[mapi * TK + slot] = i_[c];            // order irrelevant (set semantics)
    } else if (key == kv) {
      int e = atomicAdd(&s_eqn, 1);
      eqi[e] = i_[c];
    }
  }
  __syncthreads();
  int eqn = s_eqn;
  int wb = TK - need_eq;
  // equals: keep the need_eq LARGEST indices (numpy tie semantics)
  for (int e = tid; e < eqn; e += 256) {
    int myi = eqi[e];
    int bigger = 0;
    for (int f = 0; f < eqn; ++f) bigger += (eqi[f] > myi) ? 1 : 0;
    if (bigger < need_eq) pos[mapi * TK + wb + bigger] = myi;
  }
}

// ---------------- K4: indices, validity, gather + per-column f64 softmax ---------
__global__ void k_gather(const float* __restrict__ dense_ft, const float* __restrict__ maskp,
                         const unsigned char* __restrict__ qb, const int* __restrict__ pos,
                         double* __restrict__ outs, double* __restrict__ ins,
                         double* __restrict__ outs_m, double* __restrict__ ins_m,
                         int* __restrict__ voutArr, int* __restrict__ vinArr) {
  int blk = blockIdx.x;
  int mapi = blk / TK, j = blk % TK;
  int b = mapi / NFG;
  int tid = threadIdx.x;
  int p = pos[mapi * TK + j];
  int o = (int)qb[(size_t)mapi * HW + p] + 1;
  int mod4 = ((o & 3) == 0) ? 1 : 0;
  int horiz = (o == 2 || o == 6) ? 1 : 0;
  int po = (o < 4) ? 25 : -5;   // STEP*STEP : -STEP
  int pi = (o < 4) ? -5 : 1;
  int so = ((o & 1) == 0) ? -1 : 1;
  int si = -so;
  int out_idx = p + po * mod4 * WID + so * horiz;
  int in_idx  = p + pi * mod4 * WID + si * horiz;
  int ro = out_idx % 255; if (ro < 0) ro += 255;   // python floored mod
  int ri = in_idx  % 255; if (ri < 0) ri += 255;
  int vo = (ro != 0 && ro != 1 && out_idx > 0 && out_idx < HW - 1) ? 1 : 0;
  int vi = (ri != 0 && ri != 1 && in_idx  > 0 && in_idx  < HW - 1) ? 1 : 0;
  int oi = out_idx < 0 ? 0 : (out_idx > HW - 1 ? HW - 1 : out_idx);
  int ii = in_idx  < 0 ? 0 : (in_idx  > HW - 1 ? HW - 1 : in_idx);
  if (tid == 0) { voutArr[mapi * TK + j] = vo; vinArr[mapi * TK + j] = vi; }

  __shared__ double red[256];
  // dense @ oi -> outs
  {
    double x = (double)dense_ft[(size_t)(b * CH + tid) * HW + oi];
    red[tid] = x; __syncthreads();
    for (int s = 128; s > 0; s >>= 1) { if (tid < s) red[tid] = fmax(red[tid], red[tid + s]); __syncthreads(); }
    double mx = red[0]; __syncthreads();
    double e = exp(x - mx);
    red[tid] = e; __syncthreads();
    for (int s = 128; s > 0; s >>= 1) { if (tid < s) red[tid] += red[tid + s]; __syncthreads(); }
    double sm = red[0]; __syncthreads();
    outs[((size_t)mapi * TK + j) * CH + tid] = e / sm;
  }
  // dense @ ii -> ins
  {
    double x = (double)dense_ft[(size_t)(b * CH + tid) * HW + ii];
    red[tid] = x; __syncthreads();
    for (int s = 128; s > 0; s >>= 1) { if (tid < s) red[tid] = fmax(red[tid], red[tid + s]); __syncthreads(); }
    double mx = red[0]; __syncthreads();
    double e = exp(x - mx);
    red[tid] = e; __syncthreads();
    for (int s = 128; s > 0; s >>= 1) { if (tid < s) red[tid] += red[tid + s]; __syncthreads(); }
    double sm = red[0]; __syncthreads();
    ins[((size_t)mapi * TK + j) * CH + tid] = e / sm;
  }
  // mask @ oi -> outs_m
  {
    double y = (tid < CSEG) ? (double)maskp[(size_t)(b * CSEG + tid) * HW + oi] : -INFINITY;
    red[tid] = y; __syncthreads();
    for (int s = 128; s > 0; s >>= 1) { if (tid < s) red[tid] = fmax(red[tid], red[tid + s]); __syncthreads(); }
    double mx = red[0]; __syncthreads();
    double e = (tid < CSEG) ? exp(y - mx) : 0.0;
    red[tid] = e; __syncthreads();
    for (int s = 128; s > 0; s >>= 1) { if (tid < s) red[tid] += red[tid + s]; __syncthreads(); }
    double sm = red[0]; __syncthreads();
    if (tid < CSEG) outs_m[((size_t)mapi * TK + j) * CSEG + tid] = e / sm;
    __syncthreads();
  }
  // mask @ ii -> ins_m
  {
    double y = (tid < CSEG) ? (double)maskp[(size_t)(b * CSEG + tid) * HW + ii] : -INFINITY;
    red[tid] = y; __syncthreads();
    for (int s = 128; s > 0; s >>= 1) { if (tid < s) red[tid] = fmax(red[tid], red[tid + s]); __syncthreads(); }
    double mx = red[0]; __syncthreads();
    double e = (tid < CSEG) ? exp(y - mx) : 0.0;
    red[tid] = e; __syncthreads();
    for (int s = 128; s > 0; s >>= 1) { if (tid < s) red[tid] += red[tid + s]; __syncthreads(); }
    double sm = red[0]; __syncthreads();
    if (tid < CSEG) ins_m[((size_t)mapi * TK + j) * CSEG + tid] = e / sm;
  }
}

// ---------------- K5: per-map statistics + beacon in f64 (sim never materialized)
__global__ void k_stats(const double* __restrict__ outs, const double* __restrict__ ins,
                        const double* __restrict__ outs_m, const double* __restrict__ ins_m,
                        const int* __restrict__ voutArr, const int* __restrict__ vinArr,
                        const float* __restrict__ label, double* __restrict__ lossmap) {
  int mapi = blockIdx.x, tid = threadIdx.x;
  int b = mapi / NFG, c = mapi % NFG;
  __shared__ double fvo[TK], fvi[TK];
  __shared__ double avi[CH], avo[CH], avim[CSEG], avom[CSEG];
  __shared__ double rm[TK], cm[TK], rmm[TK], cmm[TK];
  __shared__ double s_sfvo, s_sfvi;
  if (tid < TK) {
    fvo[tid] = (double)voutArr[mapi * TK + tid];
    fvi[tid] = (double)vinArr[mapi * TK + tid];
  }
  __syncthreads();
  if (tid == 0) {
    double a = 0.0, d = 0.0;
    for (int j2 = 0; j2 < TK; ++j2) { a += fvo[j2]; d += fvi[j2]; }
    s_sfvo = a; s_sfvi = d;
  }
  const double* OUT  = outs   + (size_t)mapi * TK * CH;
  const double* IN   = ins    + (size_t)mapi * TK * CH;
  const double* OUTm = outs_m + (size_t)mapi * TK * CSEG;
  const double* INm  = ins_m  + (size_t)mapi * TK * CSEG;
  {
    double a = 0.0, d = 0.0;
    for (int j2 = 0; j2 < TK; ++j2) {
      a += IN[j2 * CH + tid] * fvi[j2];
      d += OUT[j2 * CH + tid] * fvo[j2];
    }
    avi[tid] = a; avo[tid] = d;
  }
  if (tid < CSEG) {
    double a = 0.0, d = 0.0;
    for (int j2 = 0; j2 < TK; ++j2) {
      a += INm[j2 * CSEG + tid] * fvi[j2];
      d += OUTm[j2 * CSEG + tid] * fvo[j2];
    }
    avim[tid] = a; avom[tid] = d;
  }
  __syncthreads();
  double ci = fmax(s_sfvi, 1.0), co = fmax(s_sfvo, 1.0);
  if (tid < TK) {
    double d1 = 0.0, d2 = 0.0, d3 = 0.0, d4 = 0.0;
    for (int e = 0; e < CH; ++e) { d1 += OUT[tid * CH + e] * avi[e]; d2 += IN[tid * CH + e] * avo[e]; }
    for (int e = 0; e < CSEG; ++e) { d3 += OUTm[tid * CSEG + e] * avim[e]; d4 += INm[tid * CSEG + e] * avom[e]; }
    rm[tid] = d1 / ci; cm[tid] = d2 / co; rmm[tid] = d3 / ci; cmm[tid] = d4 / co;
  }
  __syncthreads();
  if (tid == 0) {
    double g = 0.0, gm = 0.0;
    for (int e = 0; e < CH; ++e) g += avo[e] * avi[e];
    for (int e = 0; e < CSEG; ++e) gm += avom[e] * avim[e];
    double den = fmax(s_sfvo * s_sfvi, 1.0);
    g /= den; gm /= den;
    double loss = 0.0;
    { // row beacon: sgn_mask = rmm>gm, sgn_dense = rm>g, vals = rm, v = fvo
      double s[4] = {0, 0, 0, 0}, cn[4] = {0, 0, 0, 0};
      for (int j2 = 0; j2 < TK; ++j2) {
        int smv = rmm[j2] > gm;
        int dmv = rm[j2] > g;
        int cat = smv ? (dmv ? 3 : 0) : (dmv ? 1 : 2);  // FP,FN,TP,TN = 0,1,2,3
        s[cat] += rm[j2] * fvo[j2];
        cn[cat] += fvo[j2];
      }
      const double sg[4] = {-1.0, 1.0, 1.0, -1.0};
      for (int t = 0; t < 4; ++t)
        if (cn[t] > 0.0) loss += sg[t] * (s[t] / fmax(cn[t], 1.0));
    }
    { // col beacon: sgn_mask = cmm>gm, sgn_dense = cm>g, vals = cm, v = fvi
      double s[4] = {0, 0, 0, 0}, cn[4] = {0, 0, 0, 0};
      for (int j2 = 0; j2 < TK; ++j2) {
        int smv = cmm[j2] > gm;
        int dmv = cm[j2] > g;
        int cat = smv ? (dmv ? 3 : 0) : (dmv ? 1 : 2);
        s[cat] += cm[j2] * fvi[j2];
        cn[cat] += fvi[j2];
      }
      const double sg[4] = {-1.0, 1.0, 1.0, -1.0};
      for (int t = 0; t < 4; ++t)
        if (cn[t] > 0.0) loss += sg[t] * (s[t] / fmax(cn[t], 1.0));
    }
    float lab = label[b * CSEG + c + 1];
    double gate = (s_sfvi >= 10.0 && s_sfvo >= 10.0 && lab > 0.f) ? 1.0 : 0.0;
    lossmap[mapi] = loss * gate;
  }
}

// ---------------- K6: deterministic ordered final sum --------------------------
__global__ void k_final(const double* __restrict__ lossmap, float* __restrict__ out) {
  if (threadIdx.x == 0 && blockIdx.x == 0) {
    double s = 0.0;
    for (int i = 0; i < NMAP; ++i) s += lossmap[i];
    out[0] = (float)s;
  }
}

extern "C" void kernel_launch(void* const* d_in, const int* in_sizes, int n_in,
                              void* d_out, int out_size, void* d_ws, size_t ws_size,
                              hipStream_t stream) {
  const float* seg_map  = (const float*)d_in[0];
  const float* dense_ft = (const float*)d_in[1];
  const float* maskp    = (const float*)d_in[2];
  const float* label    = (const float*)d_in[3];
  float* outp = (float*)d_out;

  char* w = (char*)d_ws;
  double* seg = (double*)w;               w += (size_t)NB * NFG * HW * 8;
  double* mag = (double*)w;               w += (size_t)NMAP * HW * 8;
  double* outs   = (double*)w;            w += (size_t)NMAP * TK * CH * 8;
  double* ins    = (double*)w;            w += (size_t)NMAP * TK * CH * 8;
  double* outs_m = (double*)w;            w += (size_t)NMAP * TK * CSEG * 8;
  double* ins_m  = (double*)w;            w += (size_t)NMAP * TK * CSEG * 8;
  double* lossmap = (double*)w;           w += (size_t)NMAP * 8;
  unsigned long long* ckey = (unsigned long long*)w; w += (size_t)NMAP * CAND * 8;
  int* cidx = (int*)w;                    w += (size_t)NMAP * CAND * 4;
  int* pos  = (int*)w;                    w += (size_t)NMAP * TK * 4;
  int* vout = (int*)w;                    w += (size_t)NMAP * TK * 4;
  int* vin  = (int*)w;                    w += (size_t)NMAP * TK * 4;
  unsigned char* qb = (unsigned char*)w;  w += (size_t)NMAP * HW;

  k_seg<<<(NB * HW + 255) / 256, 256, 0, stream>>>(seg_map, seg);
  k_sobel<<<(NMAP * HW + 255) / 256, 256, 0, stream>>>(seg, label, mag, qb);
  k_topk_part<<<NMAP * PARTS, 256, 0, stream>>>(mag, ckey, cidx);
  k_topk_merge<<<NMAP, 256, 0, stream>>>(ckey, cidx, pos);
  k_gather<<<NMAP * TK, 256, 0, stream>>>(dense_ft, maskp, qb, pos, outs, ins,
                                          outs_m, ins_m, vout, vin);
  k_stats<<<NMAP, 256, 0, stream>>>(outs, ins, outs_m, ins_m, vout, vin, label, lossmap);
  k_final<<<1, 64, 0, stream>>>(lossmap, outp);
}

// Round 6
// 303.822 us; speedup vs baseline: 2.2816x; 1.6431x over previous
//
#include <hip/hip_runtime.h>
#include <math.h>

#define HW 65536
#define WID 256
#define HEI 256
#define NB 2
#define NFG 20
#define NMAP 40
#define CH 256
#define CSEG 21
#define TK 100
#define PARTS 32
#define PARTN (HW / PARTS)    // 2048
#define RPP (HEI / PARTS)     // 8 rows per part
#define CAND (PARTS * TK)     // 3200

__device__ __constant__ float c_GX[25] = {
  2.f,1.f,1e-6f,-1.f,-2.f,
  3.f,2.f,1e-6f,-2.f,-3.f,
  4.f,3.f,0.f,-3.f,-4.f,
  3.f,2.f,1e-6f,-2.f,-3.f,
  2.f,1.f,1e-6f,-1.f,-2.f};
__device__ __constant__ float c_GY[25] = {
  2.f,3.f,4.f,3.f,2.f,
  1.f,2.f,3.f,2.f,1.f,
  1e-6f,1e-6f,1e-6f,1e-6f,1e-6f,
  -1.f,-2.f,-3.f,-2.f,-1.f,
  -2.f,-3.f,-4.f,-3.f,-2.f};

// ---------------- K1: softmax(seg_map * 1000, axis=ch)[:,1:] in f64 ------------
__global__ void k_seg(const float* __restrict__ seg_map, double* __restrict__ seg) {
  int idx = blockIdx.x * blockDim.x + threadIdx.x;
  if (idx >= NB * HW) return;
  int b = idx / HW, p = idx % HW;
  double x[CSEG];
  double m = -INFINITY;
  #pragma unroll
  for (int c = 0; c < CSEG; ++c) {
    double v = (double)seg_map[(size_t)(b * CSEG + c) * HW + p] * 1000.0;
    x[c] = v;
    m = fmax(m, v);
  }
  double s = 0.0;
  #pragma unroll
  for (int c = 0; c < CSEG; ++c) { double e = exp(x[c] - m); x[c] = e; s += e; }
  #pragma unroll
  for (int c = 1; c < CSEG; ++c)
    seg[(size_t)(b * NFG + (c - 1)) * HW + p] = x[c] / s;
}

// ---------------- K2+K3a fused: Sobel + quantize + per-part exact top-100 -------
// Block = one 8-row slice of one map. seg tile -> LDS; mags computed into
// registers (bit-identical f64 math; zero-pad adds +0.0 which is IEEE-exact);
// tile LDS reused for keys; 8-round radix select with PARALLEL suffix-scan bin
// choice + per-wave histograms. Emits 100 candidates under (value desc, index
// desc) order (numpy argsort[::-1] tie semantics).
__global__ void k_sobel_topk(const double* __restrict__ seg, const float* __restrict__ label,
                             unsigned char* __restrict__ qb,
                             unsigned long long* __restrict__ ckey, int* __restrict__ cidx) {
  int mapi = blockIdx.x / PARTS, part = blockIdx.x % PARTS;
  int tid = threadIdx.x;
  int row0 = part * RPP;
  const double* im = seg + (size_t)mapi * HW;

  __shared__ double tile[RPP + 4][WID];        // 24576 B, later reused for keys
  __shared__ unsigned int hist4[4][256];       // 4096 B
  __shared__ int sfx[256];                     // 1024 B
  __shared__ int s_r, s_cnt, s_bsel;

  for (int r = 0; r < RPP + 4; ++r) {
    int gr = row0 - 2 + r;
    tile[r][tid] = (gr >= 0 && gr < HEI) ? im[gr * WID + tid] : 0.0;
  }
  if (tid == 0) { s_r = TK; s_cnt = 0; }
  __syncthreads();

  int b = mapi / NFG, c = mapi % NFG;
  double lab = (double)label[b * CSEG + c + 1];

  const double DIVQ = 3.1416 / 8.0;
  const double T1 = DIVQ, T3 = 3.0*DIVQ, T5 = 5.0*DIVQ, T7 = 7.0*DIVQ, T8 = 8.0*DIVQ;

  unsigned long long mykey[RPP];
  int myq[RPP];
  #pragma unroll
  for (int k = 0; k < RPP; ++k) {
    double gx = 0.0, gy = 0.0;
    #pragma unroll
    for (int dy = 0; dy < 5; ++dy) {
      #pragma unroll
      for (int dx = 0; dx < 5; ++dx) {
        int xx = tid + dx - 2;
        double v = (xx >= 0 && xx < WID) ? tile[k + dy][xx] : 0.0;
        gx += v * (double)c_GX[dy * 5 + dx];
        gy += v * (double)c_GY[dy * 5 + dx];
      }
    }
    gx *= lab; gy *= lab;
    double mg = sqrt(gx * gx + gy * gy + 1e-8);
    double o = atan2(gy, gx);
    int qv;
    if (o >= T1 && o < T3) qv = 0;
    else if (o >= T3 && o < T5) qv = 1;
    else if (o >= T5 && o < T7) qv = 2;
    else if ((o >= T7 && o < T8) || (o >= -T8 && o < -T7)) qv = 3;
    else if (o >= -T7 && o < -T5) qv = 4;
    else if (o >= -T5 && o < -T3) qv = 5;
    else if (o >= -T3 && o < -T1) qv = 6;
    else if (o >= -T1 && o < T1) qv = 7;
    else qv = 3;
    mykey[k] = (unsigned long long)__double_as_longlong(mg);
    myq[k] = qv;
  }
  __syncthreads();                 // done reading tile
  unsigned long long* sk = (unsigned long long*)&tile[0][0];   // 2048 keys, 16 KiB
  #pragma unroll
  for (int k = 0; k < RPP; ++k) {
    sk[k * WID + tid] = mykey[k];
    qb[(size_t)mapi * HW + (size_t)(row0 + k) * WID + tid] = (unsigned char)myq[k];
  }
  __syncthreads();

  // ---- 8-round radix select of the 100th-largest key (keys live in registers)
  unsigned long long pfx = 0ull, msk = 0ull;
  int w = tid >> 6;
  for (int round = 0; round < 8; ++round) {
    int shift = 56 - 8 * round;
    hist4[0][tid] = 0; hist4[1][tid] = 0; hist4[2][tid] = 0; hist4[3][tid] = 0;
    __syncthreads();
    #pragma unroll
    for (int k = 0; k < RPP; ++k) {
      unsigned long long key = mykey[k];
      if ((key & msk) == pfx)
        atomicAdd(&hist4[w][(unsigned int)(key >> shift) & 0xFFu], 1u);
    }
    __syncthreads();
    int r = s_r;   // reads complete before any write (writes occur after scan barriers)
    sfx[tid] = (int)(hist4[0][tid] + hist4[1][tid] + hist4[2][tid] + hist4[3][tid]);
    __syncthreads();
    for (int off = 1; off < 256; off <<= 1) {   // suffix inclusive scan
      int v = (tid + off < 256) ? sfx[tid + off] : 0;
      __syncthreads();
      sfx[tid] += v;
      __syncthreads();
    }
    int above = (tid == 255) ? 0 : sfx[tid + 1];
    if (sfx[tid] >= r && above < r) { s_bsel = tid; s_r = r - above; }
    __syncthreads();
    pfx |= ((unsigned long long)s_bsel << shift);
    msk |= (0xFFull << shift);
    __syncthreads();
  }
  unsigned long long kv = pfx;     // exact 100th-largest value (bit pattern)
  int need_eq = s_r;

  // ---- emit candidates: strictly-greater (any order) + largest-index equals
  unsigned long long* outk = ckey + (size_t)mapi * CAND + (size_t)part * TK;
  int* outi = cidx + (size_t)mapi * CAND + (size_t)part * TK;
  int gbase = part * PARTN;
  const int CHN = PARTN / 256;     // 8, contiguous chunk per thread
  int base = tid * CHN;
  int myeq = 0;
  for (int k = 0; k < CHN; ++k) {
    unsigned long long key = sk[base + k];
    if (key > kv) {
      int slot = atomicAdd(&s_cnt, 1);
      outk[slot] = key; outi[slot] = gbase + base + k;
    } else if (key == kv) ++myeq;
  }
  sfx[tid] = myeq;
  __syncthreads();
  for (int off = 1; off < 256; off <<= 1) {     // ascending inclusive scan
    int v = (tid >= off) ? sfx[tid - off] : 0;
    __syncthreads();
    sfx[tid] += v;
    __syncthreads();
  }
  int rank = sfx[tid] - myeq;       // exclusive prefix = ascending-index rank
  int eqtot = sfx[255];
  int lo = eqtot - need_eq;         // keep equals with rank >= lo (largest indices)
  int wb = TK - need_eq;
  for (int k = 0; k < CHN; ++k) {
    unsigned long long key = sk[base + k];
    if (key == kv) {
      if (rank >= lo) { outk[wb + rank - lo] = key; outi[wb + rank - lo] = gbase + base + k; }
      ++rank;
    }
  }
}

// ---------------- K3b: merge 3200 candidates -> exact global top-100 ------------
__global__ void k_topk_merge(const unsigned long long* __restrict__ ckey,
                             const int* __restrict__ cidx, int* __restrict__ pos) {
  int mapi = blockIdx.x, tid = threadIdx.x;
  __shared__ unsigned long long k_[CAND];       // 25.6 KiB
  __shared__ int i_[CAND];                      // 12.8 KiB
  __shared__ int eqi[CAND];                     // 12.8 KiB
  __shared__ unsigned int hist4[4][256];
  __shared__ int sfx[256];
  __shared__ int s_r, s_cnt, s_eqn, s_bsel;
  for (int c = tid; c < CAND; c += 256) {
    k_[c] = ckey[(size_t)mapi * CAND + c];
    i_[c] = cidx[(size_t)mapi * CAND + c];
  }
  if (tid == 0) { s_r = TK; s_cnt = 0; s_eqn = 0; }
  __syncthreads();
  unsigned long long pfx = 0ull, msk = 0ull;
  int w = tid >> 6;
  for (int round = 0; round < 8; ++round) {
    int shift = 56 - 8 * round;
    hist4[0][tid] = 0; hist4[1][tid] = 0; hist4[2][tid] = 0; hist4[3][tid] = 0;
    __syncthreads();
    for (int c = tid; c < CAND; c += 256) {
      unsigned long long key = k_[c];
      if ((key & msk) == pfx)
        atomicAdd(&hist4[w][(unsigned int)(key >> shift) & 0xFFu], 1u);
    }
    __syncthreads();
    int r = s_r;
    sfx[tid] = (int)(hist4[0][tid] + hist4[1][tid] + hist4[2][tid] + hist4[3][tid]);
    __syncthreads();
    for (int off = 1; off < 256; off <<= 1) {
      int v = (tid + off < 256) ? sfx[tid + off] : 0;
      __syncthreads();
      sfx[tid] += v;
      __syncthreads();
    }
    int above = (tid == 255) ? 0 : sfx[tid + 1];
    if (sfx[tid] >= r && above < r) { s_bsel = tid; s_r = r - above; }
    __syncthreads();
    pfx |= ((unsigned long long)s_bsel << shift);
    msk |= (0xFFull << shift);
    __syncthreads();
  }
  unsigned long long kv = pfx;
  int need_eq = s_r;
  for (int c = tid; c < CAND; c += 256) {
    unsigned long long key = k_[c];
    if (key > kv) {
      int slot = atomicAdd(&s_cnt, 1);
      pos[mapi * TK + slot] = i_[c];            // set semantics; order irrelevant
    } else if (key == kv) {
      int e = atomicAdd(&s_eqn, 1);
      eqi[e] = i_[c];
    }
  }
  __syncthreads();
  int eqn = s_eqn;
  int wb = TK - need_eq;
  // equals: keep the need_eq LARGEST indices (numpy tie semantics)
  for (int e = tid; e < eqn; e += 256) {
    int myi = eqi[e];
    int bigger = 0;
    for (int f = 0; f < eqn; ++f) bigger += (eqi[f] > myi) ? 1 : 0;
    if (bigger < need_eq) pos[mapi * TK + wb + bigger] = myi;
  }
}

// ---------------- K4: indices, validity, gather + per-column f64 softmax ---------
__global__ void k_gather(const float* __restrict__ dense_ft, const float* __restrict__ maskp,
                         const unsigned char* __restrict__ qb, const int* __restrict__ pos,
                         double* __restrict__ outs, double* __restrict__ ins,
                         double* __restrict__ outs_m, double* __restrict__ ins_m,
                         int* __restrict__ voutArr, int* __restrict__ vinArr) {
  int blk = blockIdx.x;
  int mapi = blk / TK, j = blk % TK;
  int b = mapi / NFG;
  int tid = threadIdx.x;
  int p = pos[mapi * TK + j];
  int o = (int)qb[(size_t)mapi * HW + p] + 1;
  int mod4 = ((o & 3) == 0) ? 1 : 0;
  int horiz = (o == 2 || o == 6) ? 1 : 0;
  int po = (o < 4) ? 25 : -5;   // STEP*STEP : -STEP
  int pi = (o < 4) ? -5 : 1;
  int so = ((o & 1) == 0) ? -1 : 1;
  int si = -so;
  int out_idx = p + po * mod4 * WID + so * horiz;
  int in_idx  = p + pi * mod4 * WID + si * horiz;
  int ro = out_idx % 255; if (ro < 0) ro += 255;   // python floored mod
  int ri = in_idx  % 255; if (ri < 0) ri += 255;
  int vo = (ro != 0 && ro != 1 && out_idx > 0 && out_idx < HW - 1) ? 1 : 0;
  int vi = (ri != 0 && ri != 1 && in_idx  > 0 && in_idx  < HW - 1) ? 1 : 0;
  int oi = out_idx < 0 ? 0 : (out_idx > HW - 1 ? HW - 1 : out_idx);
  int ii = in_idx  < 0 ? 0 : (in_idx  > HW - 1 ? HW - 1 : in_idx);
  if (tid == 0) { voutArr[mapi * TK + j] = vo; vinArr[mapi * TK + j] = vi; }

  __shared__ double red[256];
  // dense @ oi -> outs
  {
    double x = (double)dense_ft[(size_t)(b * CH + tid) * HW + oi];
    red[tid] = x; __syncthreads();
    for (int s = 128; s > 0; s >>= 1) { if (tid < s) red[tid] = fmax(red[tid], red[tid + s]); __syncthreads(); }
    double mx = red[0]; __syncthreads();
    double e = exp(x - mx);
    red[tid] = e; __syncthreads();
    for (int s = 128; s > 0; s >>= 1) { if (tid < s) red[tid] += red[tid + s]; __syncthreads(); }
    double sm = red[0]; __syncthreads();
    outs[((size_t)mapi * TK + j) * CH + tid] = e / sm;
  }
  // dense @ ii -> ins
  {
    double x = (double)dense_ft[(size_t)(b * CH + tid) * HW + ii];
    red[tid] = x; __syncthreads();
    for (int s = 128; s > 0; s >>= 1) { if (tid < s) red[tid] = fmax(red[tid], red[tid + s]); __syncthreads(); }
    double mx = red[0]; __syncthreads();
    double e = exp(x - mx);
    red[tid] = e; __syncthreads();
    for (int s = 128; s > 0; s >>= 1) { if (tid < s) red[tid] += red[tid + s]; __syncthreads(); }
    double sm = red[0]; __syncthreads();
    ins[((size_t)mapi * TK + j) * CH + tid] = e / sm;
  }
  // mask @ oi -> outs_m
  {
    double y = (tid < CSEG) ? (double)maskp[(size_t)(b * CSEG + tid) * HW + oi] : -INFINITY;
    red[tid] = y; __syncthreads();
    for (int s = 128; s > 0; s >>= 1) { if (tid < s) red[tid] = fmax(red[tid], red[tid + s]); __syncthreads(); }
    double mx = red[0]; __syncthreads();
    double e = (tid < CSEG) ? exp(y - mx) : 0.0;
    red[tid] = e; __syncthreads();
    for (int s = 128; s > 0; s >>= 1) { if (tid < s) red[tid] += red[tid + s]; __syncthreads(); }
    double sm = red[0]; __syncthreads();
    if (tid < CSEG) outs_m[((size_t)mapi * TK + j) * CSEG + tid] = e / sm;
    __syncthreads();
  }
  // mask @ ii -> ins_m
  {
    double y = (tid < CSEG) ? (double)maskp[(size_t)(b * CSEG + tid) * HW + ii] : -INFINITY;
    red[tid] = y; __syncthreads();
    for (int s = 128; s > 0; s >>= 1) { if (tid < s) red[tid] = fmax(red[tid], red[tid + s]); __syncthreads(); }
    double mx = red[0]; __syncthreads();
    double e = (tid < CSEG) ? exp(y - mx) : 0.0;
    red[tid] = e; __syncthreads();
    for (int s = 128; s > 0; s >>= 1) { if (tid < s) red[tid] += red[tid + s]; __syncthreads(); }
    double sm = red[0]; __syncthreads();
    if (tid < CSEG) ins_m[((size_t)mapi * TK + j) * CSEG + tid] = e / sm;
  }
}

// ---------------- K5: per-map statistics + beacon in f64 (sim never materialized)
__global__ void k_stats(const double* __restrict__ outs, const double* __restrict__ ins,
                        const double* __restrict__ outs_m, const double* __restrict__ ins_m,
                        const int* __restrict__ voutArr, const int* __restrict__ vinArr,
                        const float* __restrict__ label, double* __restrict__ lossmap) {
  int mapi = blockIdx.x, tid = threadIdx.x;
  int b = mapi / NFG, c = mapi % NFG;
  __shared__ double fvo[TK], fvi[TK];
  __shared__ double avi[CH], avo[CH], avim[CSEG], avom[CSEG];
  __shared__ double rm[TK], cm[TK], rmm[TK], cmm[TK];
  __shared__ double s_sfvo, s_sfvi;
  if (tid < TK) {
    fvo[tid] = (double)voutArr[mapi * TK + tid];
    fvi[tid] = (double)vinArr[mapi * TK + tid];
  }
  __syncthreads();
  if (tid == 0) {
    double a = 0.0, d = 0.0;
    for (int j2 = 0; j2 < TK; ++j2) { a += fvo[j2]; d += fvi[j2]; }
    s_sfvo = a; s_sfvi = d;
  }
  const double* OUT  = outs   + (size_t)mapi * TK * CH;
  const double* IN   = ins    + (size_t)mapi * TK * CH;
  const double* OUTm = outs_m + (size_t)mapi * TK * CSEG;
  const double* INm  = ins_m  + (size_t)mapi * TK * CSEG;
  {
    double a = 0.0, d = 0.0;
    for (int j2 = 0; j2 < TK; ++j2) {
      a += IN[j2 * CH + tid] * fvi[j2];
      d += OUT[j2 * CH + tid] * fvo[j2];
    }
    avi[tid] = a; avo[tid] = d;
  }
  if (tid < CSEG) {
    double a = 0.0, d = 0.0;
    for (int j2 = 0; j2 < TK; ++j2) {
      a += INm[j2 * CSEG + tid] * fvi[j2];
      d += OUTm[j2 * CSEG + tid] * fvo[j2];
    }
    avim[tid] = a; avom[tid] = d;
  }
  __syncthreads();
  double ci = fmax(s_sfvi, 1.0), co = fmax(s_sfvo, 1.0);
  if (tid < TK) {
    double d1 = 0.0, d2 = 0.0, d3 = 0.0, d4 = 0.0;
    for (int e = 0; e < CH; ++e) { d1 += OUT[tid * CH + e] * avi[e]; d2 += IN[tid * CH + e] * avo[e]; }
    for (int e = 0; e < CSEG; ++e) { d3 += OUTm[tid * CSEG + e] * avim[e]; d4 += INm[tid * CSEG + e] * avom[e]; }
    rm[tid] = d1 / ci; cm[tid] = d2 / co; rmm[tid] = d3 / ci; cmm[tid] = d4 / co;
  }
  __syncthreads();
  if (tid == 0) {
    double g = 0.0, gm = 0.0;
    for (int e = 0; e < CH; ++e) g += avo[e] * avi[e];
    for (int e = 0; e < CSEG; ++e) gm += avom[e] * avim[e];
    double den = fmax(s_sfvo * s_sfvi, 1.0);
    g /= den; gm /= den;
    double loss = 0.0;
    { // row beacon: sgn_mask = rmm>gm, sgn_dense = rm>g, vals = rm, v = fvo
      double s[4] = {0, 0, 0, 0}, cn[4] = {0, 0, 0, 0};
      for (int j2 = 0; j2 < TK; ++j2) {
        int smv = rmm[j2] > gm;
        int dmv = rm[j2] > g;
        int cat = smv ? (dmv ? 3 : 0) : (dmv ? 1 : 2);  // FP,FN,TP,TN = 0,1,2,3
        s[cat] += rm[j2] * fvo[j2];
        cn[cat] += fvo[j2];
      }
      const double sg[4] = {-1.0, 1.0, 1.0, -1.0};
      for (int t = 0; t < 4; ++t)
        if (cn[t] > 0.0) loss += sg[t] * (s[t] / fmax(cn[t], 1.0));
    }
    { // col beacon: sgn_mask = cmm>gm, sgn_dense = cm>g, vals = cm, v = fvi
      double s[4] = {0, 0, 0, 0}, cn[4] = {0, 0, 0, 0};
      for (int j2 = 0; j2 < TK; ++j2) {
        int smv = cmm[j2] > gm;
        int dmv = cm[j2] > g;
        int cat = smv ? (dmv ? 3 : 0) : (dmv ? 1 : 2);
        s[cat] += cm[j2] * fvi[j2];
        cn[cat] += fvi[j2];
      }
      const double sg[4] = {-1.0, 1.0, 1.0, -1.0};
      for (int t = 0; t < 4; ++t)
        if (cn[t] > 0.0) loss += sg[t] * (s[t] / fmax(cn[t], 1.0));
    }
    float lab = label[b * CSEG + c + 1];
    double gate = (s_sfvi >= 10.0 && s_sfvo >= 10.0 && lab > 0.f) ? 1.0 : 0.0;
    lossmap[mapi] = loss * gate;
  }
}

// ---------------- K6: deterministic ordered final sum --------------------------
__global__ void k_final(const double* __restrict__ lossmap, float* __restrict__ out) {
  if (threadIdx.x == 0 && blockIdx.x == 0) {
    double s = 0.0;
    for (int i = 0; i < NMAP; ++i) s += lossmap[i];
    out[0] = (float)s;
  }
}

extern "C" void kernel_launch(void* const* d_in, const int* in_sizes, int n_in,
                              void* d_out, int out_size, void* d_ws, size_t ws_size,
                              hipStream_t stream) {
  const float* seg_map  = (const float*)d_in[0];
  const float* dense_ft = (const float*)d_in[1];
  const float* maskp    = (const float*)d_in[2];
  const float* label    = (const float*)d_in[3];
  float* outp = (float*)d_out;

  char* w = (char*)d_ws;
  double* seg = (double*)w;               w += (size_t)NB * NFG * HW * 8;
  double* outs   = (double*)w;            w += (size_t)NMAP * TK * CH * 8;
  double* ins    = (double*)w;            w += (size_t)NMAP * TK * CH * 8;
  double* outs_m = (double*)w;            w += (size_t)NMAP * TK * CSEG * 8;
  double* ins_m  = (double*)w;            w += (size_t)NMAP * TK * CSEG * 8;
  double* lossmap = (double*)w;           w += (size_t)NMAP * 8;
  unsigned long long* ckey = (unsigned long long*)w; w += (size_t)NMAP * CAND * 8;
  int* cidx = (int*)w;                    w += (size_t)NMAP * CAND * 4;
  int* pos  = (int*)w;                    w += (size_t)NMAP * TK * 4;
  int* vout = (int*)w;                    w += (size_t)NMAP * TK * 4;
  int* vin  = (int*)w;                    w += (size_t)NMAP * TK * 4;
  unsigned char* qb = (unsigned char*)w;  w += (size_t)NMAP * HW;

  k_seg<<<(NB * HW + 255) / 256, 256, 0, stream>>>(seg_map, seg);
  k_sobel_topk<<<NMAP * PARTS, 256, 0, stream>>>(seg, label, qb, ckey, cidx);
  k_topk_merge<<<NMAP, 256, 0, stream>>>(ckey, cidx, pos);
  k_gather<<<NMAP * TK, 256, 0, stream>>>(dense_ft, maskp, qb, pos, outs, ins,
                                          outs_m, ins_m, vout, vin);
  k_stats<<<NMAP, 256, 0, stream>>>(outs, ins, outs_m, ins_m, vout, vin, label, lossmap);
  k_final<<<1, 64, 0, stream>>>(lossmap, outp);
}

// Round 7
// 215.560 us; speedup vs baseline: 3.2158x; 1.4095x over previous
//
#include <hip/hip_runtime.h>
#include <math.h>

#define HW 65536
#define WID 256
#define HEI 256
#define NB 2
#define NFG 20
#define NMAP 40
#define CH 256
#define CSEG 21
#define TK 100
#define PARTS 32
#define PARTN (HW / PARTS)    // 2048
#define RPP (HEI / PARTS)     // 8 rows per part
#define CAND (PARTS * TK)     // 3200

__device__ __constant__ float c_GX[25] = {
  2.f,1.f,1e-6f,-1.f,-2.f,
  3.f,2.f,1e-6f,-2.f,-3.f,
  4.f,3.f,0.f,-3.f,-4.f,
  3.f,2.f,1e-6f,-2.f,-3.f,
  2.f,1.f,1e-6f,-1.f,-2.f};
__device__ __constant__ float c_GY[25] = {
  2.f,3.f,4.f,3.f,2.f,
  1.f,2.f,3.f,2.f,1.f,
  1e-6f,1e-6f,1e-6f,1e-6f,1e-6f,
  -1.f,-2.f,-3.f,-2.f,-1.f,
  -2.f,-3.f,-4.f,-3.f,-2.f};

// ---------------- K1: softmax(seg_map * 1000, axis=ch)[:,1:] in f64 ------------
__global__ __launch_bounds__(256) void k_seg(const float* __restrict__ seg_map,
                                             double* __restrict__ seg) {
  int idx = blockIdx.x * blockDim.x + threadIdx.x;
  if (idx >= NB * HW) return;
  int b = idx / HW, p = idx % HW;
  double x[CSEG];
  double m = -INFINITY;
  #pragma unroll
  for (int c = 0; c < CSEG; ++c) {
    double v = (double)seg_map[(size_t)(b * CSEG + c) * HW + p] * 1000.0;
    x[c] = v;
    m = fmax(m, v);
  }
  double s = 0.0;
  #pragma unroll
  for (int c = 0; c < CSEG; ++c) { double e = exp(x[c] - m); x[c] = e; s += e; }
  #pragma unroll
  for (int c = 1; c < CSEG; ++c)
    seg[(size_t)(b * NFG + (c - 1)) * HW + p] = x[c] / s;
}

// ---------------- K2+K3a fused: Sobel + quantize + per-part exact top-100 -------
// Identical FP math to the passing round-6 kernel. Mechanics only: keys kept in
// LDS (no long-lived register arrays -> no scratch), wave-shfl scans instead of
// LDS doubling scans. Numpy argsort[::-1] tie semantics (largest index first).
__global__ __launch_bounds__(256) void k_sobel_topk(
    const double* __restrict__ seg, const float* __restrict__ label,
    unsigned char* __restrict__ qb,
    unsigned long long* __restrict__ ckey, int* __restrict__ cidx) {
  int mapi = blockIdx.x / PARTS, part = blockIdx.x % PARTS;
  int tid = threadIdx.x;
  int lane = tid & 63, w = tid >> 6;
  int row0 = part * RPP;
  const double* im = seg + (size_t)mapi * HW;

  __shared__ double tile[RPP + 4][WID];        // 24576 B, later reused for keys
  __shared__ unsigned int hist4[4][256];       // 4096 B
  __shared__ int sfx[256];                     // 1024 B
  __shared__ int wtot[4];
  __shared__ int s_r, s_cnt, s_bsel;

  for (int r = 0; r < RPP + 4; ++r) {
    int gr = row0 - 2 + r;
    tile[r][tid] = (gr >= 0 && gr < HEI) ? im[gr * WID + tid] : 0.0;
  }
  if (tid == 0) { s_r = TK; s_cnt = 0; }
  __syncthreads();

  int b = mapi / NFG, c = mapi % NFG;
  double lab = (double)label[b * CSEG + c + 1];
  const double DIVQ = 3.1416 / 8.0;
  const double T1 = DIVQ, T3 = 3.0*DIVQ, T5 = 5.0*DIVQ, T7 = 7.0*DIVQ, T8 = 8.0*DIVQ;

  unsigned long long mykey[RPP];               // short-lived; dies after sk store
  #pragma unroll
  for (int k = 0; k < RPP; ++k) {
    double gx = 0.0, gy = 0.0;
    #pragma unroll
    for (int dy = 0; dy < 5; ++dy) {
      #pragma unroll
      for (int dx = 0; dx < 5; ++dx) {
        int xx = tid + dx - 2;
        double v = (xx >= 0 && xx < WID) ? tile[k + dy][xx] : 0.0;
        gx += v * (double)c_GX[dy * 5 + dx];
        gy += v * (double)c_GY[dy * 5 + dx];
      }
    }
    gx *= lab; gy *= lab;
    double mg = sqrt(gx * gx + gy * gy + 1e-8);
    double o = atan2(gy, gx);
    int qv;
    if (o >= T1 && o < T3) qv = 0;
    else if (o >= T3 && o < T5) qv = 1;
    else if (o >= T5 && o < T7) qv = 2;
    else if ((o >= T7 && o < T8) || (o >= -T8 && o < -T7)) qv = 3;
    else if (o >= -T7 && o < -T5) qv = 4;
    else if (o >= -T5 && o < -T3) qv = 5;
    else if (o >= -T3 && o < -T1) qv = 6;
    else if (o >= -T1 && o < T1) qv = 7;
    else qv = 3;
    mykey[k] = (unsigned long long)__double_as_longlong(mg);
    qb[(size_t)mapi * HW + (size_t)(row0 + k) * WID + tid] = (unsigned char)qv;
  }
  __syncthreads();                 // done reading tile
  unsigned long long* sk = (unsigned long long*)&tile[0][0];   // 2048 keys
  #pragma unroll
  for (int k = 0; k < RPP; ++k) sk[k * WID + tid] = mykey[k];
  __syncthreads();

  // ---- 8-round radix select of the 100th-largest key (keys read from LDS)
  unsigned long long pfx = 0ull, msk = 0ull;
  for (int round = 0; round < 8; ++round) {
    int shift = 56 - 8 * round;
    hist4[0][tid] = 0; hist4[1][tid] = 0; hist4[2][tid] = 0; hist4[3][tid] = 0;
    __syncthreads();
    #pragma unroll
    for (int k = 0; k < RPP; ++k) {
      unsigned long long key = sk[k * WID + tid];
      if ((key & msk) == pfx)
        atomicAdd(&hist4[w][(unsigned int)(key >> shift) & 0xFFu], 1u);
    }
    __syncthreads();
    int r = s_r;                   // s_r stable (last write >=2 barriers ago)
    int v = (int)(hist4[0][tid] + hist4[1][tid] + hist4[2][tid] + hist4[3][tid]);
    #pragma unroll
    for (int off = 1; off < 64; off <<= 1) {   // wave inclusive SUFFIX scan
      int u = __shfl_down(v, off, 64);
      if (lane + off < 64) v += u;
    }
    if (lane == 0) wtot[w] = v;
    __syncthreads();
    int add = 0;
    for (int ww = w + 1; ww < 4; ++ww) add += wtot[ww];
    v += add;                      // inclusive suffix sum over all 256 bins
    sfx[tid] = v;
    __syncthreads();
    int above = (tid == 255) ? 0 : sfx[tid + 1];
    if (v >= r && above < r) { s_bsel = tid; s_r = r - above; }
    __syncthreads();
    pfx |= ((unsigned long long)s_bsel << shift);
    msk |= (0xFFull << shift);
  }
  unsigned long long kv = pfx;     // exact 100th-largest value (bit pattern)
  int need_eq = s_r;

  // ---- emit candidates: strictly-greater (any order) + largest-index equals
  unsigned long long* outk = ckey + (size_t)mapi * CAND + (size_t)part * TK;
  int* outi = cidx + (size_t)mapi * CAND + (size_t)part * TK;
  int gbase = part * PARTN;
  const int CHN = PARTN / 256;     // 8, contiguous chunk per thread (index order)
  int base = tid * CHN;
  int myeq = 0;
  for (int k = 0; k < CHN; ++k) {
    unsigned long long key = sk[base + k];
    if (key > kv) {
      int slot = atomicAdd(&s_cnt, 1);
      outk[slot] = key; outi[slot] = gbase + base + k;
    } else if (key == kv) ++myeq;
  }
  int v2 = myeq;                   // ascending inclusive scan over 256 threads
  #pragma unroll
  for (int off = 1; off < 64; off <<= 1) {
    int u = __shfl_up(v2, off, 64);
    if (lane >= off) v2 += u;
  }
  if (lane == 63) wtot[w] = v2;
  __syncthreads();
  int addl = 0;
  for (int ww = 0; ww < w; ++ww) addl += wtot[ww];
  int incl = v2 + addl;
  int rank = incl - myeq;          // exclusive prefix = ascending-index rank
  int eqtot = wtot[0] + wtot[1] + wtot[2] + wtot[3];
  int lo = eqtot - need_eq;        // keep equals with rank >= lo (largest indices)
  int wb = TK - need_eq;
  for (int k = 0; k < CHN; ++k) {
    unsigned long long key = sk[base + k];
    if (key == kv) {
      if (rank >= lo) { outk[wb + rank - lo] = key; outi[wb + rank - lo] = gbase + base + k; }
      ++rank;
    }
  }
}

// ---------------- K3b: merge 3200 candidates -> exact global top-100 ------------
__global__ __launch_bounds__(256) void k_topk_merge(
    const unsigned long long* __restrict__ ckey,
    const int* __restrict__ cidx, int* __restrict__ pos) {
  int mapi = blockIdx.x, tid = threadIdx.x;
  int lane = tid & 63, w = tid >> 6;
  __shared__ unsigned long long k_[CAND];       // 25.6 KiB
  __shared__ int i_[CAND];                      // 12.8 KiB
  __shared__ int eqi[CAND];                     // 12.8 KiB
  __shared__ unsigned int hist4[4][256];
  __shared__ int sfx[256];
  __shared__ int wtot[4];
  __shared__ int s_r, s_cnt, s_eqn, s_bsel;
  for (int c = tid; c < CAND; c += 256) {
    k_[c] = ckey[(size_t)mapi * CAND + c];
    i_[c] = cidx[(size_t)mapi * CAND + c];
  }
  if (tid == 0) { s_r = TK; s_cnt = 0; s_eqn = 0; }
  __syncthreads();
  unsigned long long pfx = 0ull, msk = 0ull;
  for (int round = 0; round < 8; ++round) {
    int shift = 56 - 8 * round;
    hist4[0][tid] = 0; hist4[1][tid] = 0; hist4[2][tid] = 0; hist4[3][tid] = 0;
    __syncthreads();
    for (int c = tid; c < CAND; c += 256) {
      unsigned long long key = k_[c];
      if ((key & msk) == pfx)
        atomicAdd(&hist4[w][(unsigned int)(key >> shift) & 0xFFu], 1u);
    }
    __syncthreads();
    int r = s_r;
    int v = (int)(hist4[0][tid] + hist4[1][tid] + hist4[2][tid] + hist4[3][tid]);
    #pragma unroll
    for (int off = 1; off < 64; off <<= 1) {
      int u = __shfl_down(v, off, 64);
      if (lane + off < 64) v += u;
    }
    if (lane == 0) wtot[w] = v;
    __syncthreads();
    int add = 0;
    for (int ww = w + 1; ww < 4; ++ww) add += wtot[ww];
    v += add;
    sfx[tid] = v;
    __syncthreads();
    int above = (tid == 255) ? 0 : sfx[tid + 1];
    if (v >= r && above < r) { s_bsel = tid; s_r = r - above; }
    __syncthreads();
    pfx |= ((unsigned long long)s_bsel << shift);
    msk |= (0xFFull << shift);
  }
  unsigned long long kv = pfx;
  int need_eq = s_r;
  for (int c = tid; c < CAND; c += 256) {
    unsigned long long key = k_[c];
    if (key > kv) {
      int slot = atomicAdd(&s_cnt, 1);
      pos[mapi * TK + slot] = i_[c];            // set semantics; order irrelevant
    } else if (key == kv) {
      int e = atomicAdd(&s_eqn, 1);
      eqi[e] = i_[c];
    }
  }
  __syncthreads();
  int eqn = s_eqn;
  int wb = TK - need_eq;
  // equals: keep the need_eq LARGEST indices (numpy tie semantics)
  for (int e = tid; e < eqn; e += 256) {
    int myi = eqi[e];
    int bigger = 0;
    for (int f = 0; f < eqn; ++f) bigger += (eqi[f] > myi) ? 1 : 0;
    if (bigger < need_eq) pos[mapi * TK + wb + bigger] = myi;
  }
}

// ---------------- K4: indices, validity, gather + per-column f64 softmax ---------
__global__ __launch_bounds__(256) void k_gather(
    const float* __restrict__ dense_ft, const float* __restrict__ maskp,
    const unsigned char* __restrict__ qb, const int* __restrict__ pos,
    double* __restrict__ outs, double* __restrict__ ins,
    double* __restrict__ outs_m, double* __restrict__ ins_m,
    int* __restrict__ voutArr, int* __restrict__ vinArr) {
  int blk = blockIdx.x;
  int mapi = blk / TK, j = blk % TK;
  int b = mapi / NFG;
  int tid = threadIdx.x;
  int p = pos[mapi * TK + j];
  int o = (int)qb[(size_t)mapi * HW + p] + 1;
  int mod4 = ((o & 3) == 0) ? 1 : 0;
  int horiz = (o == 2 || o == 6) ? 1 : 0;
  int po = (o < 4) ? 25 : -5;   // STEP*STEP : -STEP
  int pi = (o < 4) ? -5 : 1;
  int so = ((o & 1) == 0) ? -1 : 1;
  int si = -so;
  int out_idx = p + po * mod4 * WID + so * horiz;
  int in_idx  = p + pi * mod4 * WID + si * horiz;
  int ro = out_idx % 255; if (ro < 0) ro += 255;   // python floored mod
  int ri = in_idx  % 255; if (ri < 0) ri += 255;
  int vo = (ro != 0 && ro != 1 && out_idx > 0 && out_idx < HW - 1) ? 1 : 0;
  int vi = (ri != 0 && ri != 1 && in_idx  > 0 && in_idx  < HW - 1) ? 1 : 0;
  int oi = out_idx < 0 ? 0 : (out_idx > HW - 1 ? HW - 1 : out_idx);
  int ii = in_idx  < 0 ? 0 : (in_idx  > HW - 1 ? HW - 1 : in_idx);
  if (tid == 0) { voutArr[mapi * TK + j] = vo; vinArr[mapi * TK + j] = vi; }

  __shared__ double red[256];
  // dense @ oi -> outs
  {
    double x = (double)dense_ft[(size_t)(b * CH + tid) * HW + oi];
    red[tid] = x; __syncthreads();
    for (int s = 128; s > 0; s >>= 1) { if (tid < s) red[tid] = fmax(red[tid], red[tid + s]); __syncthreads(); }
    double mx = red[0]; __syncthreads();
    double e = exp(x - mx);
    red[tid] = e; __syncthreads();
    for (int s = 128; s > 0; s >>= 1) { if (tid < s) red[tid] += red[tid + s]; __syncthreads(); }
    double sm = red[0]; __syncthreads();
    outs[((size_t)mapi * TK + j) * CH + tid] = e / sm;
  }
  // dense @ ii -> ins
  {
    double x = (double)dense_ft[(size_t)(b * CH + tid) * HW + ii];
    red[tid] = x; __syncthreads();
    for (int s = 128; s > 0; s >>= 1) { if (tid < s) red[tid] = fmax(red[tid], red[tid + s]); __syncthreads(); }
    double mx = red[0]; __syncthreads();
    double e = exp(x - mx);
    red[tid] = e; __syncthreads();
    for (int s = 128; s > 0; s >>= 1) { if (tid < s) red[tid] += red[tid + s]; __syncthreads(); }
    double sm = red[0]; __syncthreads();
    ins[((size_t)mapi * TK + j) * CH + tid] = e / sm;
  }
  // mask @ oi -> outs_m
  {
    double y = (tid < CSEG) ? (double)maskp[(size_t)(b * CSEG + tid) * HW + oi] : -INFINITY;
    red[tid] = y; __syncthreads();
    for (int s = 128; s > 0; s >>= 1) { if (tid < s) red[tid] = fmax(red[tid], red[tid + s]); __syncthreads(); }
    double mx = red[0]; __syncthreads();
    double e = (tid < CSEG) ? exp(y - mx) : 0.0;
    red[tid] = e; __syncthreads();
    for (int s = 128; s > 0; s >>= 1) { if (tid < s) red[tid] += red[tid + s]; __syncthreads(); }
    double sm = red[0]; __syncthreads();
    if (tid < CSEG) outs_m[((size_t)mapi * TK + j) * CSEG + tid] = e / sm;
    __syncthreads();
  }
  // mask @ ii -> ins_m
  {
    double y = (tid < CSEG) ? (double)maskp[(size_t)(b * CSEG + tid) * HW + ii] : -INFINITY;
    red[tid] = y; __syncthreads();
    for (int s = 128; s > 0; s >>= 1) { if (tid < s) red[tid] = fmax(red[tid], red[tid + s]); __syncthreads(); }
    double mx = red[0]; __syncthreads();
    double e = (tid < CSEG) ? exp(y - mx) : 0.0;
    red[tid] = e; __syncthreads();
    for (int s = 128; s > 0; s >>= 1) { if (tid < s) red[tid] += red[tid + s]; __syncthreads(); }
    double sm = red[0]; __syncthreads();
    if (tid < CSEG) ins_m[((size_t)mapi * TK + j) * CSEG + tid] = e / sm;
  }
}

// ---------------- K5: per-map statistics + beacon in f64 (sim never materialized)
__global__ __launch_bounds__(256) void k_stats(
    const double* __restrict__ outs, const double* __restrict__ ins,
    const double* __restrict__ outs_m, const double* __restrict__ ins_m,
    const int* __restrict__ voutArr, const int* __restrict__ vinArr,
    const float* __restrict__ label, double* __restrict__ lossmap) {
  int mapi = blockIdx.x, tid = threadIdx.x;
  int b = mapi / NFG, c = mapi % NFG;
  __shared__ double fvo[TK], fvi[TK];
  __shared__ double avi[CH], avo[CH], avim[CSEG], avom[CSEG];
  __shared__ double rm[TK], cm[TK], rmm[TK], cmm[TK];
  __shared__ double s_sfvo, s_sfvi;
  if (tid < TK) {
    fvo[tid] = (double)voutArr[mapi * TK + tid];
    fvi[tid] = (double)vinArr[mapi * TK + tid];
  }
  __syncthreads();
  if (tid == 0) {
    double a = 0.0, d = 0.0;
    for (int j2 = 0; j2 < TK; ++j2) { a += fvo[j2]; d += fvi[j2]; }
    s_sfvo = a; s_sfvi = d;
  }
  const double* OUT  = outs   + (size_t)mapi * TK * CH;
  const double* IN   = ins    + (size_t)mapi * TK * CH;
  const double* OUTm = outs_m + (size_t)mapi * TK * CSEG;
  const double* INm  = ins_m  + (size_t)mapi * TK * CSEG;
  {
    double a = 0.0, d = 0.0;
    for (int j2 = 0; j2 < TK; ++j2) {
      a += IN[j2 * CH + tid] * fvi[j2];
      d += OUT[j2 * CH + tid] * fvo[j2];
    }
    avi[tid] = a; avo[tid] = d;
  }
  if (tid < CSEG) {
    double a = 0.0, d = 0.0;
    for (int j2 = 0; j2 < TK; ++j2) {
      a += INm[j2 * CSEG + tid] * fvi[j2];
      d += OUTm[j2 * CSEG + tid] * fvo[j2];
    }
    avim[tid] = a; avom[tid] = d;
  }
  __syncthreads();
  double ci = fmax(s_sfvi, 1.0), co = fmax(s_sfvo, 1.0);
  if (tid < TK) {
    double d1 = 0.0, d2 = 0.0, d3 = 0.0, d4 = 0.0;
    for (int e = 0; e < CH; ++e) { d1 += OUT[tid * CH + e] * avi[e]; d2 += IN[tid * CH + e] * avo[e]; }
    for (int e = 0; e < CSEG; ++e) { d3 += OUTm[tid * CSEG + e] * avim[e]; d4 += INm[tid * CSEG + e] * avom[e]; }
    rm[tid] = d1 / ci; cm[tid] = d2 / co; rmm[tid] = d3 / ci; cmm[tid] = d4 / co;
  }
  __syncthreads();
  if (tid == 0) {
    double g = 0.0, gm = 0.0;
    for (int e = 0; e < CH; ++e) g += avo[e] * avi[e];
    for (int e = 0; e < CSEG; ++e) gm += avom[e] * avim[e];
    double den = fmax(s_sfvo * s_sfvi, 1.0);
    g /= den; gm /= den;
    double loss = 0.0;
    { // row beacon: sgn_mask = rmm>gm, sgn_dense = rm>g, vals = rm, v = fvo
      double s[4] = {0, 0, 0, 0}, cn[4] = {0, 0, 0, 0};
      for (int j2 = 0; j2 < TK; ++j2) {
        int smv = rmm[j2] > gm;
        int dmv = rm[j2] > g;
        int cat = smv ? (dmv ? 3 : 0) : (dmv ? 1 : 2);  // FP,FN,TP,TN = 0,1,2,3
        s[cat] += rm[j2] * fvo[j2];
        cn[cat] += fvo[j2];
      }
      const double sg[4] = {-1.0, 1.0, 1.0, -1.0};
      for (int t = 0; t < 4; ++t)
        if (cn[t] > 0.0) loss += sg[t] * (s[t] / fmax(cn[t], 1.0));
    }
    { // col beacon: sgn_mask = cmm>gm, sgn_dense = cm>g, vals = cm, v = fvi
      double s[4] = {0, 0, 0, 0}, cn[4] = {0, 0, 0, 0};
      for (int j2 = 0; j2 < TK; ++j2) {
        int smv = cmm[j2] > gm;
        int dmv = cm[j2] > g;
        int cat = smv ? (dmv ? 3 : 0) : (dmv ? 1 : 2);
        s[cat] += cm[j2] * fvi[j2];
        cn[cat] += fvi[j2];
      }
      const double sg[4] = {-1.0, 1.0, 1.0, -1.0};
      for (int t = 0; t < 4; ++t)
        if (cn[t] > 0.0) loss += sg[t] * (s[t] / fmax(cn[t], 1.0));
    }
    float lab = label[b * CSEG + c + 1];
    double gate = (s_sfvi >= 10.0 && s_sfvo >= 10.0 && lab > 0.f) ? 1.0 : 0.0;
    lossmap[mapi] = loss * gate;
  }
}

// ---------------- K6: deterministic ordered final sum --------------------------
__global__ __launch_bounds__(64) void k_final(const double* __restrict__ lossmap,
                                              float* __restrict__ out) {
  if (threadIdx.x == 0 && blockIdx.x == 0) {
    double s = 0.0;
    for (int i = 0; i < NMAP; ++i) s += lossmap[i];
    out[0] = (float)s;
  }
}

extern "C" void kernel_launch(void* const* d_in, const int* in_sizes, int n_in,
                              void* d_out, int out_size, void* d_ws, size_t ws_size,
                              hipStream_t stream) {
  const float* seg_map  = (const float*)d_in[0];
  const float* dense_ft = (const float*)d_in[1];
  const float* maskp    = (const float*)d_in[2];
  const float* label    = (const float*)d_in[3];
  float* outp = (float*)d_out;

  char* w = (char*)d_ws;
  double* seg = (double*)w;               w += (size_t)NB * NFG * HW * 8;
  double* outs   = (double*)w;            w += (size_t)NMAP * TK * CH * 8;
  double* ins    = (double*)w;            w += (size_t)NMAP * TK * CH * 8;
  double* outs_m = (double*)w;            w += (size_t)NMAP * TK * CSEG * 8;
  double* ins_m  = (double*)w;            w += (size_t)NMAP * TK * CSEG * 8;
  double* lossmap = (double*)w;           w += (size_t)NMAP * 8;
  unsigned long long* ckey = (unsigned long long*)w; w += (size_t)NMAP * CAND * 8;
  int* cidx = (int*)w;                    w += (size_t)NMAP * CAND * 4;
  int* pos  = (int*)w;                    w += (size_t)NMAP * TK * 4;
  int* vout = (int*)w;                    w += (size_t)NMAP * TK * 4;
  int* vin  = (int*)w;                    w += (size_t)NMAP * TK * 4;
  unsigned char* qb = (unsigned char*)w;  w += (size_t)NMAP * HW;

  k_seg<<<(NB * HW + 255) / 256, 256, 0, stream>>>(seg_map, seg);
  k_sobel_topk<<<NMAP * PARTS, 256, 0, stream>>>(seg, label, qb, ckey, cidx);
  k_topk_merge<<<NMAP, 256, 0, stream>>>(ckey, cidx, pos);
  k_gather<<<NMAP * TK, 256, 0, stream>>>(dense_ft, maskp, qb, pos, outs, ins,
                                          outs_m, ins_m, vout, vin);
  k_stats<<<NMAP, 256, 0, stream>>>(outs, ins, outs_m, ins_m, vout, vin, label, lossmap);
  k_final<<<1, 64, 0, stream>>>(lossmap, outp);
}

// Round 8
// 199.540 us; speedup vs baseline: 3.4740x; 1.0803x over previous
//
#include <hip/hip_runtime.h>
#include <math.h>

#define HW 65536
#define WID 256
#define HEI 256
#define NB 2
#define NFG 20
#define NMAP 40
#define CH 256
#define CSEG 21
#define TK 100
#define PARTS 32
#define PARTN (HW / PARTS)    // 2048
#define RPP (HEI / PARTS)     // 8 rows per part
#define CAND (PARTS * TK)     // 3200

__device__ __constant__ float c_GX[25] = {
  2.f,1.f,1e-6f,-1.f,-2.f,
  3.f,2.f,1e-6f,-2.f,-3.f,
  4.f,3.f,0.f,-3.f,-4.f,
  3.f,2.f,1e-6f,-2.f,-3.f,
  2.f,1.f,1e-6f,-1.f,-2.f};
__device__ __constant__ float c_GY[25] = {
  2.f,3.f,4.f,3.f,2.f,
  1.f,2.f,3.f,2.f,1.f,
  1e-6f,1e-6f,1e-6f,1e-6f,1e-6f,
  -1.f,-2.f,-3.f,-2.f,-1.f,
  -2.f,-3.f,-4.f,-3.f,-2.f};

// ---------------- K1: softmax(seg_map * 1000, axis=ch)[:,1:] in f64 ------------
// exp(d)=+0.0 exactly for d<-745.2 (IEEE underflow) -> skip the libm call.
__global__ __launch_bounds__(256) void k_seg(const float* __restrict__ seg_map,
                                             double* __restrict__ seg) {
  int idx = blockIdx.x * blockDim.x + threadIdx.x;
  if (idx >= NB * HW) return;
  int b = idx / HW, p = idx % HW;
  double x[CSEG];
  double m = -INFINITY;
  #pragma unroll
  for (int c = 0; c < CSEG; ++c) {
    double v = (double)seg_map[(size_t)(b * CSEG + c) * HW + p] * 1000.0;
    x[c] = v;
    m = fmax(m, v);
  }
  double s = 0.0;
  #pragma unroll
  for (int c = 0; c < CSEG; ++c) {
    double d = x[c] - m;
    double e = (d < -746.0) ? 0.0 : exp(d);   // bit-identical to exp(d)
    x[c] = e; s += e;
  }
  #pragma unroll
  for (int c = 1; c < CSEG; ++c)
    seg[(size_t)(b * NFG + (c - 1)) * HW + p] = x[c] / s;
}

// ---------------- K2+K3a fused: Sobel + quantize + per-part exact top-100 -------
// FP math bit-identical to the passing kernel. Radix rounds: keys in VGPRs,
// 3 barriers/round, lane-local bin selection (bin tid wins iff v>=r && v-cnt<r).
// Numpy argsort[::-1] tie semantics (largest index first among equals).
__global__ __launch_bounds__(256) void k_sobel_topk(
    const double* __restrict__ seg, const float* __restrict__ label,
    unsigned char* __restrict__ qb,
    unsigned long long* __restrict__ ckey, int* __restrict__ cidx) {
  int mapi = blockIdx.x / PARTS, part = blockIdx.x % PARTS;
  int tid = threadIdx.x;
  int lane = tid & 63, w = tid >> 6;
  int row0 = part * RPP;
  const double* im = seg + (size_t)mapi * HW;

  __shared__ double tile[RPP + 4][WID];        // 24576 B, reused for keys
  __shared__ unsigned int hist4[4][256];       // 4096 B
  __shared__ int wtot[4];
  __shared__ int s_r, s_cnt, s_bsel;

  for (int r = 0; r < RPP + 4; ++r) {
    int gr = row0 - 2 + r;
    tile[r][tid] = (gr >= 0 && gr < HEI) ? im[gr * WID + tid] : 0.0;
  }
  hist4[0][tid] = 0; hist4[1][tid] = 0; hist4[2][tid] = 0; hist4[3][tid] = 0;
  if (tid == 0) { s_r = TK; s_cnt = 0; }
  __syncthreads();

  int b = mapi / NFG, c = mapi % NFG;
  double lab = (double)label[b * CSEG + c + 1];
  const double DIVQ = 3.1416 / 8.0;
  const double T1 = DIVQ, T3 = 3.0*DIVQ, T5 = 5.0*DIVQ, T7 = 7.0*DIVQ, T8 = 8.0*DIVQ;

  unsigned long long mykey[RPP];               // register-resident (cap=256, no spill)
  #pragma unroll
  for (int k = 0; k < RPP; ++k) {
    double gx = 0.0, gy = 0.0;
    #pragma unroll
    for (int dy = 0; dy < 5; ++dy) {
      #pragma unroll
      for (int dx = 0; dx < 5; ++dx) {
        int xx = tid + dx - 2;
        double v = (xx >= 0 && xx < WID) ? tile[k + dy][xx] : 0.0;
        gx += v * (double)c_GX[dy * 5 + dx];
        gy += v * (double)c_GY[dy * 5 + dx];
      }
    }
    gx *= lab; gy *= lab;
    double mg = sqrt(gx * gx + gy * gy + 1e-8);
    double o = atan2(gy, gx);
    int qv;
    if (o >= T1 && o < T3) qv = 0;
    else if (o >= T3 && o < T5) qv = 1;
    else if (o >= T5 && o < T7) qv = 2;
    else if ((o >= T7 && o < T8) || (o >= -T8 && o < -T7)) qv = 3;
    else if (o >= -T7 && o < -T5) qv = 4;
    else if (o >= -T5 && o < -T3) qv = 5;
    else if (o >= -T3 && o < -T1) qv = 6;
    else if (o >= -T1 && o < T1) qv = 7;
    else qv = 3;
    mykey[k] = (unsigned long long)__double_as_longlong(mg);
    qb[(size_t)mapi * HW + (size_t)(row0 + k) * WID + tid] = (unsigned char)qv;
  }
  __syncthreads();                 // done reading tile
  unsigned long long* sk = (unsigned long long*)&tile[0][0];   // 2048 keys
  #pragma unroll
  for (int k = 0; k < RPP; ++k) sk[k * WID + tid] = mykey[k];
  __syncthreads();                 // sk ready for extraction

  // ---- 8-round radix select, 3 barriers/round
  unsigned long long pfx = 0ull, msk = 0ull;
  for (int round = 0; round < 8; ++round) {
    int shift = 56 - 8 * round;
    #pragma unroll
    for (int k = 0; k < RPP; ++k) {
      unsigned long long key = mykey[k];
      if ((key & msk) == pfx)
        atomicAdd(&hist4[w][(unsigned int)(key >> shift) & 0xFFu], 1u);
    }
    __syncthreads();               // B1: atomics visible
    int r = s_r;
    int cnt = (int)(hist4[0][tid] + hist4[1][tid] + hist4[2][tid] + hist4[3][tid]);
    hist4[0][tid] = 0; hist4[1][tid] = 0; hist4[2][tid] = 0; hist4[3][tid] = 0;  // owner-clear
    int v = cnt;
    #pragma unroll
    for (int off = 1; off < 64; off <<= 1) {   // wave inclusive SUFFIX scan
      int u = __shfl_down(v, off, 64);
      if (lane + off < 64) v += u;
    }
    if (lane == 0) wtot[w] = v;
    __syncthreads();               // B2: wtot visible
    int add = 0;
    for (int ww = w + 1; ww < 4; ++ww) add += wtot[ww];
    v += add;                      // inclusive suffix over all 256 bins
    if (v >= r && v - cnt < r) { s_bsel = tid; s_r = r - (v - cnt); }  // unique bin
    __syncthreads();               // B3: s_bsel/s_r visible
    pfx |= ((unsigned long long)s_bsel << shift);
    msk |= (0xFFull << shift);
  }
  unsigned long long kv = pfx;     // exact 100th-largest value (bit pattern)
  int need_eq = s_r;

  // ---- emit candidates: strictly-greater (any order) + largest-index equals
  unsigned long long* outk = ckey + (size_t)mapi * CAND + (size_t)part * TK;
  int* outi = cidx + (size_t)mapi * CAND + (size_t)part * TK;
  int gbase = part * PARTN;
  const int CHN = PARTN / 256;     // 8, contiguous chunk per thread (index order)
  int base = tid * CHN;
  int myeq = 0;
  for (int k = 0; k < CHN; ++k) {
    unsigned long long key = sk[base + k];
    if (key > kv) {
      int slot = atomicAdd(&s_cnt, 1);
      outk[slot] = key; outi[slot] = gbase + base + k;
    } else if (key == kv) ++myeq;
  }
  int v2 = myeq;                   // ascending inclusive scan over 256 threads
  #pragma unroll
  for (int off = 1; off < 64; off <<= 1) {
    int u = __shfl_up(v2, off, 64);
    if (lane >= off) v2 += u;
  }
  if (lane == 63) wtot[w] = v2;
  __syncthreads();
  int addl = 0;
  for (int ww = 0; ww < w; ++ww) addl += wtot[ww];
  int incl = v2 + addl;
  int rank = incl - myeq;          // exclusive prefix = ascending-index rank
  int eqtot = wtot[0] + wtot[1] + wtot[2] + wtot[3];
  int lo = eqtot - need_eq;        // keep equals with rank >= lo (largest indices)
  int wb = TK - need_eq;
  for (int k = 0; k < CHN; ++k) {
    unsigned long long key = sk[base + k];
    if (key == kv) {
      if (rank >= lo) { outk[wb + rank - lo] = key; outi[wb + rank - lo] = gbase + base + k; }
      ++rank;
    }
  }
}

// ---------------- K3b: merge 3200 candidates -> exact global top-100 ------------
__global__ __launch_bounds__(256) void k_topk_merge(
    const unsigned long long* __restrict__ ckey,
    const int* __restrict__ cidx, int* __restrict__ pos) {
  int mapi = blockIdx.x, tid = threadIdx.x;
  int lane = tid & 63, w = tid >> 6;
  __shared__ unsigned long long k_[CAND];       // 25.6 KiB
  __shared__ int i_[CAND];                      // 12.8 KiB
  __shared__ int eqi[CAND];                     // 12.8 KiB
  __shared__ unsigned int hist4[4][256];
  __shared__ int wtot[4];
  __shared__ int s_r, s_cnt, s_eqn, s_bsel;
  for (int c = tid; c < CAND; c += 256) {
    k_[c] = ckey[(size_t)mapi * CAND + c];
    i_[c] = cidx[(size_t)mapi * CAND + c];
  }
  hist4[0][tid] = 0; hist4[1][tid] = 0; hist4[2][tid] = 0; hist4[3][tid] = 0;
  if (tid == 0) { s_r = TK; s_cnt = 0; s_eqn = 0; }
  __syncthreads();
  unsigned long long pfx = 0ull, msk = 0ull;
  for (int round = 0; round < 8; ++round) {
    int shift = 56 - 8 * round;
    for (int c = tid; c < CAND; c += 256) {
      unsigned long long key = k_[c];
      if ((key & msk) == pfx)
        atomicAdd(&hist4[w][(unsigned int)(key >> shift) & 0xFFu], 1u);
    }
    __syncthreads();               // B1
    int r = s_r;
    int cnt = (int)(hist4[0][tid] + hist4[1][tid] + hist4[2][tid] + hist4[3][tid]);
    hist4[0][tid] = 0; hist4[1][tid] = 0; hist4[2][tid] = 0; hist4[3][tid] = 0;
    int v = cnt;
    #pragma unroll
    for (int off = 1; off < 64; off <<= 1) {
      int u = __shfl_down(v, off, 64);
      if (lane + off < 64) v += u;
    }
    if (lane == 0) wtot[w] = v;
    __syncthreads();               // B2
    int add = 0;
    for (int ww = w + 1; ww < 4; ++ww) add += wtot[ww];
    v += add;
    if (v >= r && v - cnt < r) { s_bsel = tid; s_r = r - (v - cnt); }
    __syncthreads();               // B3
    pfx |= ((unsigned long long)s_bsel << shift);
    msk |= (0xFFull << shift);
  }
  unsigned long long kv = pfx;
  int need_eq = s_r;
  for (int c = tid; c < CAND; c += 256) {
    unsigned long long key = k_[c];
    if (key > kv) {
      int slot = atomicAdd(&s_cnt, 1);
      pos[mapi * TK + slot] = i_[c];            // set semantics; order irrelevant
    } else if (key == kv) {
      int e = atomicAdd(&s_eqn, 1);
      eqi[e] = i_[c];
    }
  }
  __syncthreads();
  int eqn = s_eqn;
  int wb = TK - need_eq;
  // equals: keep the need_eq LARGEST indices (numpy tie semantics)
  for (int e = tid; e < eqn; e += 256) {
    int myi = eqi[e];
    int bigger = 0;
    for (int f = 0; f < eqn; ++f) bigger += (eqi[f] > myi) ? 1 : 0;
    if (bigger < need_eq) pos[mapi * TK + wb + bigger] = myi;
  }
}

// ---------------- K4: gather + per-column f64 softmax, one wave per softmax -----
// Zero __syncthreads: wave0=dense@oi, wave1=dense@ii, wave2=mask@oi, wave3=mask@ii.
__global__ __launch_bounds__(256) void k_gather(
    const float* __restrict__ dense_ft, const float* __restrict__ maskp,
    const unsigned char* __restrict__ qb, const int* __restrict__ pos,
    double* __restrict__ outs, double* __restrict__ ins,
    double* __restrict__ outs_m, double* __restrict__ ins_m,
    int* __restrict__ voutArr, int* __restrict__ vinArr) {
  int blk = blockIdx.x;
  int mapi = blk / TK, j = blk % TK;
  int b = mapi / NFG;
  int tid = threadIdx.x;
  int lane = tid & 63, w = tid >> 6;
  int p = pos[mapi * TK + j];
  int o = (int)qb[(size_t)mapi * HW + p] + 1;
  int mod4 = ((o & 3) == 0) ? 1 : 0;
  int horiz = (o == 2 || o == 6) ? 1 : 0;
  int po = (o < 4) ? 25 : -5;   // STEP*STEP : -STEP
  int pi = (o < 4) ? -5 : 1;
  int so = ((o & 1) == 0) ? -1 : 1;
  int si = -so;
  int out_idx = p + po * mod4 * WID + so * horiz;
  int in_idx  = p + pi * mod4 * WID + si * horiz;
  int ro = out_idx % 255; if (ro < 0) ro += 255;   // python floored mod
  int ri = in_idx  % 255; if (ri < 0) ri += 255;
  int vo = (ro != 0 && ro != 1 && out_idx > 0 && out_idx < HW - 1) ? 1 : 0;
  int vi = (ri != 0 && ri != 1 && in_idx  > 0 && in_idx  < HW - 1) ? 1 : 0;
  int oi = out_idx < 0 ? 0 : (out_idx > HW - 1 ? HW - 1 : out_idx);
  int ii = in_idx  < 0 ? 0 : (in_idx  > HW - 1 ? HW - 1 : in_idx);
  if (tid == 0) { voutArr[mapi * TK + j] = vo; vinArr[mapi * TK + j] = vi; }

  if (w < 2) {
    int idx = (w == 0) ? oi : ii;
    double x[4];
    double mx = -INFINITY;
    #pragma unroll
    for (int q = 0; q < 4; ++q) {
      x[q] = (double)dense_ft[(size_t)(b * CH + lane + 64 * q) * HW + idx];
      mx = fmax(mx, x[q]);
    }
    #pragma unroll
    for (int off = 1; off < 64; off <<= 1) mx = fmax(mx, __shfl_xor(mx, off, 64));
    double e[4], s = 0.0;
    #pragma unroll
    for (int q = 0; q < 4; ++q) { e[q] = exp(x[q] - mx); s += e[q]; }
    #pragma unroll
    for (int off = 1; off < 64; off <<= 1) s += __shfl_xor(s, off, 64);
    double* dst = ((w == 0) ? outs : ins) + ((size_t)mapi * TK + j) * CH;
    #pragma unroll
    for (int q = 0; q < 4; ++q) dst[lane + 64 * q] = e[q] / s;
  } else {
    int idx = (w == 2) ? oi : ii;
    double y = (lane < CSEG) ? (double)maskp[(size_t)(b * CSEG + lane) * HW + idx]
                             : -INFINITY;
    double mx = y;
    #pragma unroll
    for (int off = 1; off < 64; off <<= 1) mx = fmax(mx, __shfl_xor(mx, off, 64));
    double e = (lane < CSEG) ? exp(y - mx) : 0.0;
    double s = e;
    #pragma unroll
    for (int off = 1; off < 64; off <<= 1) s += __shfl_xor(s, off, 64);
    if (lane < CSEG)
      (((w == 2) ? outs_m : ins_m) + ((size_t)mapi * TK + j) * CSEG)[lane] = e / s;
  }
}

// ---------------- K5: per-map statistics + beacon in f64 (sim never materialized)
__global__ __launch_bounds__(256) void k_stats(
    const double* __restrict__ outs, const double* __restrict__ ins,
    const double* __restrict__ outs_m, const double* __restrict__ ins_m,
    const int* __restrict__ voutArr, const int* __restrict__ vinArr,
    const float* __restrict__ label, double* __restrict__ lossmap) {
  int mapi = blockIdx.x, tid = threadIdx.x;
  int b = mapi / NFG, c = mapi % NFG;
  __shared__ double fvo[TK], fvi[TK];
  __shared__ double avi[CH], avo[CH], avim[CSEG], avom[CSEG];
  __shared__ double rm[TK], cm[TK], rmm[TK], cmm[TK];
  __shared__ double s_sfvo, s_sfvi;
  if (tid < TK) {
    fvo[tid] = (double)voutArr[mapi * TK + tid];
    fvi[tid] = (double)vinArr[mapi * TK + tid];
  }
  __syncthreads();
  if (tid == 0) {
    double a = 0.0, d = 0.0;
    for (int j2 = 0; j2 < TK; ++j2) { a += fvo[j2]; d += fvi[j2]; }
    s_sfvo = a; s_sfvi = d;
  }
  const double* OUT  = outs   + (size_t)mapi * TK * CH;
  const double* IN   = ins    + (size_t)mapi * TK * CH;
  const double* OUTm = outs_m + (size_t)mapi * TK * CSEG;
  const double* INm  = ins_m  + (size_t)mapi * TK * CSEG;
  {
    double a = 0.0, d = 0.0;
    for (int j2 = 0; j2 < TK; ++j2) {
      a += IN[j2 * CH + tid] * fvi[j2];
      d += OUT[j2 * CH + tid] * fvo[j2];
    }
    avi[tid] = a; avo[tid] = d;
  }
  if (tid < CSEG) {
    double a = 0.0, d = 0.0;
    for (int j2 = 0; j2 < TK; ++j2) {
      a += INm[j2 * CSEG + tid] * fvi[j2];
      d += OUTm[j2 * CSEG + tid] * fvo[j2];
    }
    avim[tid] = a; avom[tid] = d;
  }
  __syncthreads();
  double ci = fmax(s_sfvi, 1.0), co = fmax(s_sfvo, 1.0);
  if (tid < TK) {
    double d1 = 0.0, d2 = 0.0, d3 = 0.0, d4 = 0.0;
    for (int e = 0; e < CH; ++e) { d1 += OUT[tid * CH + e] * avi[e]; d2 += IN[tid * CH + e] * avo[e]; }
    for (int e = 0; e < CSEG; ++e) { d3 += OUTm[tid * CSEG + e] * avim[e]; d4 += INm[tid * CSEG + e] * avom[e]; }
    rm[tid] = d1 / ci; cm[tid] = d2 / co; rmm[tid] = d3 / ci; cmm[tid] = d4 / co;
  }
  __syncthreads();
  if (tid == 0) {
    double g = 0.0, gm = 0.0;
    for (int e = 0; e < CH; ++e) g += avo[e] * avi[e];
    for (int e = 0; e < CSEG; ++e) gm += avom[e] * avim[e];
    double den = fmax(s_sfvo * s_sfvi, 1.0);
    g /= den; gm /= den;
    double loss = 0.0;
    { // row beacon: sgn_mask = rmm>gm, sgn_dense = rm>g, vals = rm, v = fvo
      double s[4] = {0, 0, 0, 0}, cn[4] = {0, 0, 0, 0};
      for (int j2 = 0; j2 < TK; ++j2) {
        int smv = rmm[j2] > gm;
        int dmv = rm[j2] > g;
        int cat = smv ? (dmv ? 3 : 0) : (dmv ? 1 : 2);  // FP,FN,TP,TN = 0,1,2,3
        s[cat] += rm[j2] * fvo[j2];
        cn[cat] += fvo[j2];
      }
      const double sg[4] = {-1.0, 1.0, 1.0, -1.0};
      for (int t = 0; t < 4; ++t)
        if (cn[t] > 0.0) loss += sg[t] * (s[t] / fmax(cn[t], 1.0));
    }
    { // col beacon: sgn_mask = cmm>gm, sgn_dense = cm>g, vals = cm, v = fvi
      double s[4] = {0, 0, 0, 0}, cn[4] = {0, 0, 0, 0};
      for (int j2 = 0; j2 < TK; ++j2) {
        int smv = cmm[j2] > gm;
        int dmv = cm[j2] > g;
        int cat = smv ? (dmv ? 3 : 0) : (dmv ? 1 : 2);
        s[cat] += cm[j2] * fvi[j2];
        cn[cat] += fvi[j2];
      }
      const double sg[4] = {-1.0, 1.0, 1.0, -1.0};
      for (int t = 0; t < 4; ++t)
        if (cn[t] > 0.0) loss += sg[t] * (s[t] / fmax(cn[t], 1.0));
    }
    float lab = label[b * CSEG + c + 1];
    double gate = (s_sfvi >= 10.0 && s_sfvo >= 10.0 && lab > 0.f) ? 1.0 : 0.0;
    lossmap[mapi] = loss * gate;
  }
}

// ---------------- K6: deterministic ordered final sum --------------------------
__global__ __launch_bounds__(64) void k_final(const double* __restrict__ lossmap,
                                              float* __restrict__ out) {
  if (threadIdx.x == 0 && blockIdx.x == 0) {
    double s = 0.0;
    for (int i = 0; i < NMAP; ++i) s += lossmap[i];
    out[0] = (float)s;
  }
}

extern "C" void kernel_launch(void* const* d_in, const int* in_sizes, int n_in,
                              void* d_out, int out_size, void* d_ws, size_t ws_size,
                              hipStream_t stream) {
  const float* seg_map  = (const float*)d_in[0];
  const float* dense_ft = (const float*)d_in[1];
  const float* maskp    = (const float*)d_in[2];
  const float* label    = (const float*)d_in[3];
  float* outp = (float*)d_out;

  char* w = (char*)d_ws;
  double* seg = (double*)w;               w += (size_t)NB * NFG * HW * 8;
  double* outs   = (double*)w;            w += (size_t)NMAP * TK * CH * 8;
  double* ins    = (double*)w;            w += (size_t)NMAP * TK * CH * 8;
  double* outs_m = (double*)w;            w += (size_t)NMAP * TK * CSEG * 8;
  double* ins_m  = (double*)w;            w += (size_t)NMAP * TK * CSEG * 8;
  double* lossmap = (double*)w;           w += (size_t)NMAP * 8;
  unsigned long long* ckey = (unsigned long long*)w; w += (size_t)NMAP * CAND * 8;
  int* cidx = (int*)w;                    w += (size_t)NMAP * CAND * 4;
  int* pos  = (int*)w;                    w += (size_t)NMAP * TK * 4;
  int* vout = (int*)w;                    w += (size_t)NMAP * TK * 4;
  int* vin  = (int*)w;                    w += (size_t)NMAP * TK * 4;
  unsigned char* qb = (unsigned char*)w;  w += (size_t)NMAP * HW;

  k_seg<<<(NB * HW + 255) / 256, 256, 0, stream>>>(seg_map, seg);
  k_sobel_topk<<<NMAP * PARTS, 256, 0, stream>>>(seg, label, qb, ckey, cidx);
  k_topk_merge<<<NMAP, 256, 0, stream>>>(ckey, cidx, pos);
  k_gather<<<NMAP * TK, 256, 0, stream>>>(dense_ft, maskp, qb, pos, outs, ins,
                                          outs_m, ins_m, vout, vin);
  k_stats<<<NMAP, 256, 0, stream>>>(outs, ins, outs_m, ins_m, vout, vin, label, lossmap);
  k_final<<<1, 64, 0, stream>>>(lossmap, outp);
}